// Round 11
// baseline (474.776 us; speedup 1.0000x reference)
//
#include <hip/hip_runtime.h>
#include <cstdint>
#include <cstddef>

#define DEVINL __device__ __forceinline__

typedef float    f32x4 __attribute__((ext_vector_type(4)));
typedef _Float16 f16x8 __attribute__((ext_vector_type(8)));
typedef _Float16 f16x4 __attribute__((ext_vector_type(4)));

// ---------------- constants ----------------
constexpr int BB = 16, NN = 2048, MM = 32768;

// ---------------- ws layout (bytes) ----------------
constexpr size_t OFF_WE1 = 0;                           // 128x64 f16 (Kp padded 6->64)
constexpr size_t OFF_WE2 = OFF_WE1 + 128 * 64 * 2;
constexpr size_t OFF_W1  = OFF_WE2 + 128 * 128 * 2;
constexpr size_t OFF_W2  = OFF_W1  + 3 * 128 * 128 * 2;
constexpr size_t OFF_WF  = OFF_W2  + 3 * 128 * 128 * 2;
constexpr size_t OFF_WC1 = OFF_WF  + 1024 * 384 * 2;
constexpr size_t OFF_WC2 = OFF_WC1 + 512 * 1024 * 2;
constexpr size_t OFF_WC3 = OFF_WC2 + 256 * 512 * 2;     // 128x256 (Opad 50->128)
constexpr size_t OFF_BC2 = OFF_WC3 + 128 * 256 * 2;     // 256 f32
constexpr size_t OFF_BC3 = OFF_BC2 + 256 * 4;           // 128 f32
constexpr size_t OFF_CVEC= OFF_BC3 + 128 * 4;           // 16x512 f32
constexpr size_t OFF_PMAX= OFF_CVEC+ 16 * 512 * 4;      // 16x1024 mapped-uint (atomic max)
constexpr size_t OFF_PSUM= OFF_PMAX+ 16 * 1024 * 4;     // 16x1024 f32 (atomic add)
constexpr size_t OFF_IDX = OFF_PSUM+ 16 * 1024 * 4;
constexpr size_t OFF_R1  = 8ull << 20;                  // > OFF_IDX + 2MB
constexpr size_t OFF_X0  = OFF_R1;                      // 4MB  (M x 64 f16, k-padded)
constexpr size_t OFF_HT  = OFF_R1 + (4ull  << 20);      // 8MB  (M x 128 f16)
constexpr size_t OFF_TT  = OFF_R1 + (12ull << 20);      // 8MB
constexpr size_t OFF_MT  = OFF_R1 + (20ull << 20);      // 8MB
constexpr size_t OFF_C1  = OFF_R1;                      // 32MB (M x 512 f16), aliases x0/h/t/m (dead)
constexpr size_t OFF_XCAT= OFF_R1 + (32ull << 20);      // 24MB (M x 384 f16)
constexpr size_t OFF_C2  = OFF_XCAT;                    // 16MB (M x 256 f16), aliases xcat (dead)
constexpr size_t OFF_XF  = OFF_XCAT + (24ull << 20);    // 64MB (M x 1024 f16)

DEVINL unsigned fmap(float f) {            // order-preserving float->uint
    unsigned u = __float_as_uint(f);
    return (u & 0x80000000u) ? ~u : (u | 0x80000000u);
}
DEVINL float funmap(unsigned u) {
    return (u & 0x80000000u) ? __uint_as_float(u & 0x7FFFFFFFu) : __uint_as_float(~u);
}

// ---------------- fold-all: weights (f16, BN-folded), biases, x0 prep, pool-acc init ----------------
__global__ __launch_bounds__(256) void fold_all_kernel(
    const float* We1, const float* ge1, const float* We2, const float* ge2,
    const float* W1,  const float* g1,  const float* W2,  const float* g2,
    const float* Wf,  const float* gf,  const float* Wc1, const float* gc1,
    const float* Wc2, const float* gc2, const float* Wc3,
    const float* gc2b, const float* bc2, const float* bb2, const float* bc3,
    const float* pts, char* ws)
{
    const int bid = blockIdx.x;
    const int tid = threadIdx.x;

    if (bid == 4704) {
        ((float*)(ws + OFF_BC2))[tid] = gc2b[tid] * bc2[tid] + bb2[tid];
        return;
    }
    if (bid == 4705) {
        if (tid < 128) ((float*)(ws + OFF_BC3))[tid] = (tid < 50) ? bc3[tid] : 0.f;
        return;
    }
    if (bid >= 4834) {           // pool accumulator init: pmax (mapped) = 0, psum = 0
        int f = (bid - 4834) * 256 + tid;
        if (f < 16384) ((unsigned*)(ws + OFF_PMAX))[f] = 0u;
        else           ((float*)   (ws + OFF_PSUM))[f - 16384] = 0.f;
        return;
    }
    if (bid >= 4706) {           // x0 prep: (B,6,N) f32 -> (M x 64) f16 K-contig, zero pad
        int m = (bid - 4706) * 256 + tid;
        int b = m >> 11, n = m & 2047;
        const float* ps = pts + (size_t)b * 6 * 2048 + n;
        _Float16 tmp[64];
#pragma unroll
        for (int c = 0; c < 64; ++c) tmp[c] = (_Float16)0.f;
#pragma unroll
        for (int c = 0; c < 6; ++c) tmp[c] = (_Float16)ps[(size_t)c << 11];
        _Float16* dst = (_Float16*)(ws + OFF_X0) + (size_t)m * 64;
#pragma unroll
        for (int v = 0; v < 8; ++v) *(f16x8*)(dst + v * 8) = *(const f16x8*)(tmp + v * 8);
        return;
    }

    int id, base;
    if      (bid < 32)   { id = 0;  base = 0;    }
    else if (bid < 96)   { id = 1;  base = 32;   }
    else if (bid < 160)  { id = 2;  base = 96;   }
    else if (bid < 224)  { id = 3;  base = 160;  }
    else if (bid < 288)  { id = 4;  base = 224;  }
    else if (bid < 352)  { id = 5;  base = 288;  }
    else if (bid < 416)  { id = 6;  base = 352;  }
    else if (bid < 480)  { id = 7;  base = 416;  }
    else if (bid < 2016) { id = 8;  base = 480;  }
    else if (bid < 4064) { id = 9;  base = 2016; }
    else if (bid < 4576) { id = 10; base = 4064; }
    else                 { id = 11; base = 4576; }

    const float* src = nullptr; const float* g = nullptr; _Float16* dst = nullptr;
    int O = 0, K = 0, lds = 0, Kp = 0;
    switch (id) {
        case 0:  src = We1; g = ge1; O = 128; K = 6;    lds = 6;    Kp = 64;   dst = (_Float16*)(ws + OFF_WE1); break;
        case 1:  src = We2; g = ge2; O = 128; K = 128;  lds = 128;  Kp = 128;  dst = (_Float16*)(ws + OFF_WE2); break;
        case 2: case 3: case 4: {
            int i = id - 2;
            src = W1 + (size_t)i * 16384; g = g1 + i * 128; O = 128; K = 128; lds = 128; Kp = 128;
            dst = (_Float16*)(ws + OFF_W1) + (size_t)i * 16384; break; }
        case 5: case 6: case 7: {
            int i = id - 5;
            src = W2 + (size_t)i * 16384; g = g2 + i * 128; O = 128; K = 128; lds = 128; Kp = 128;
            dst = (_Float16*)(ws + OFF_W2) + (size_t)i * 16384; break; }
        case 8:  src = Wf;  g = gf;  O = 1024; K = 384;  lds = 384;  Kp = 384;  dst = (_Float16*)(ws + OFF_WF);  break;
        case 9:  src = Wc1; g = gc1; O = 512;  K = 1024; lds = 3136; Kp = 1024; dst = (_Float16*)(ws + OFF_WC1); break;
        case 10: src = Wc2; g = gc2; O = 256;  K = 512;  lds = 512;  Kp = 512;  dst = (_Float16*)(ws + OFF_WC2); break;
        default: src = Wc3; g = nullptr; O = 50; K = 256; lds = 256; Kp = 256;  dst = (_Float16*)(ws + OFF_WC3); break;
    }
    int e = (bid - base) * 256 + tid;
    int o = e / Kp, k = e - o * Kp;
    float v = 0.f;
    if (o < O && k < K) {
        v = src[(size_t)o * lds + k];
        if (g) v *= g[o];
    }
    dst[e] = (_Float16)v;
}

// ---------------- KNN: fused select+collect, in-wave bitonic tournament merge ----------------
DEVINL float knn_dist(const float4 pq, const float4 pm) {
    float t = pq.x * pm.x;
    t = fmaf(pq.y, pm.y, t);
    t = fmaf(pq.z, pm.z, t);
    return fmaf(-2.f, t, pm.w);
}

#define KNN_DINS(X) do { \
    const float x_ = (X); \
    d15 = __builtin_amdgcn_fmed3f(x_, d14, d15); \
    d14 = __builtin_amdgcn_fmed3f(x_, d13, d14); \
    d13 = __builtin_amdgcn_fmed3f(x_, d12, d13); \
    d12 = __builtin_amdgcn_fmed3f(x_, d11, d12); \
    d11 = __builtin_amdgcn_fmed3f(x_, d10, d11); \
    d10 = __builtin_amdgcn_fmed3f(x_, d9,  d10); \
    d9  = __builtin_amdgcn_fmed3f(x_, d8,  d9);  \
    d8  = __builtin_amdgcn_fmed3f(x_, d7,  d8);  \
    d7  = __builtin_amdgcn_fmed3f(x_, d6,  d7);  \
    d6  = __builtin_amdgcn_fmed3f(x_, d5,  d6);  \
    d5  = __builtin_amdgcn_fmed3f(x_, d4,  d5);  \
    d4  = __builtin_amdgcn_fmed3f(x_, d3,  d4);  \
    d3  = __builtin_amdgcn_fmed3f(x_, d2,  d3);  \
    d2  = __builtin_amdgcn_fmed3f(x_, d1,  d2);  \
    d1  = __builtin_amdgcn_fmed3f(x_, d0,  d1);  \
    d0  = __builtin_amdgcn_fmed3f(x_, -3.4e38f, d0); \
} while (0)

#define KNN_CE(A, B) { const float lo_ = fminf(A, B), hi_ = fmaxf(A, B); A = lo_; B = hi_; }

#define KNN_MERGE(OFF) do { \
    const float n0  = __shfl_xor(d0,  OFF), n1  = __shfl_xor(d1,  OFF), \
                n2  = __shfl_xor(d2,  OFF), n3  = __shfl_xor(d3,  OFF), \
                n4  = __shfl_xor(d4,  OFF), n5  = __shfl_xor(d5,  OFF), \
                n6  = __shfl_xor(d6,  OFF), n7  = __shfl_xor(d7,  OFF), \
                n8  = __shfl_xor(d8,  OFF), n9  = __shfl_xor(d9,  OFF), \
                n10 = __shfl_xor(d10, OFF), n11 = __shfl_xor(d11, OFF), \
                n12 = __shfl_xor(d12, OFF), n13 = __shfl_xor(d13, OFF), \
                n14 = __shfl_xor(d14, OFF), n15 = __shfl_xor(d15, OFF); \
    d0  = fminf(d0,  n15); d1  = fminf(d1,  n14); d2  = fminf(d2,  n13); d3  = fminf(d3,  n12); \
    d4  = fminf(d4,  n11); d5  = fminf(d5,  n10); d6  = fminf(d6,  n9);  d7  = fminf(d7,  n8);  \
    d8  = fminf(d8,  n7);  d9  = fminf(d9,  n6);  d10 = fminf(d10, n5);  d11 = fminf(d11, n4);  \
    d12 = fminf(d12, n3);  d13 = fminf(d13, n2);  d14 = fminf(d14, n1);  d15 = fminf(d15, n0);  \
    KNN_CE(d0, d8)  KNN_CE(d1, d9)  KNN_CE(d2, d10) KNN_CE(d3, d11) \
    KNN_CE(d4, d12) KNN_CE(d5, d13) KNN_CE(d6, d14) KNN_CE(d7, d15) \
    KNN_CE(d0, d4)  KNN_CE(d1, d5)  KNN_CE(d2, d6)  KNN_CE(d3, d7)  \
    KNN_CE(d8, d12) KNN_CE(d9, d13) KNN_CE(d10,d14) KNN_CE(d11,d15) \
    KNN_CE(d0, d2)  KNN_CE(d1, d3)  KNN_CE(d4, d6)  KNN_CE(d5, d7)  \
    KNN_CE(d8, d10) KNN_CE(d9, d11) KNN_CE(d12,d14) KNN_CE(d13,d15) \
    KNN_CE(d0, d1)  KNN_CE(d2, d3)  KNN_CE(d4, d5)  KNN_CE(d6, d7)  \
    KNN_CE(d8, d9)  KNN_CE(d10,d11) KNN_CE(d12,d13) KNN_CE(d14,d15) \
} while (0)

__global__ __launch_bounds__(256) void knn_kernel(const float* __restrict__ pts, int* __restrict__ idxout)
{
    __shared__ float4 P[2048];       // 32KB, stays intact for the rescan
    __shared__ int    cnt[32];
    const int tid = threadIdx.x;
    const int b = blockIdx.x;
    const float* pb = pts + (size_t)b * 6 * 2048;
    for (int i = tid; i < 2048; i += 256) {
        float x = pb[i];
        float y = pb[2048 + i];
        float z = pb[4096 + i];
        P[i] = make_float4(x, y, z, x * x + y * y + z * z);
    }
    if (tid < 32) cnt[tid] = 0;
    __syncthreads();

    const int p = tid & 7;          // candidate partition (m == 8*it + p)
    const int g = tid >> 3;         // query within block (0..31)
    const int q = blockIdx.y * 32 + g;
    const float4 pq = P[q];

    float d0 = 3.4e38f, d1 = 3.4e38f, d2 = 3.4e38f, d3 = 3.4e38f,
          d4 = 3.4e38f, d5 = 3.4e38f, d6 = 3.4e38f, d7 = 3.4e38f,
          d8 = 3.4e38f, d9 = 3.4e38f, d10 = 3.4e38f, d11 = 3.4e38f,
          d12 = 3.4e38f, d13 = 3.4e38f, d14 = 3.4e38f, d15 = 3.4e38f;

    float4 nxt = P[p];
#pragma unroll 2
    for (int it = 0; it < 256; ++it) {
        const float4 pm = nxt;
        const int m = it * 8 + p;
        nxt = P[(m + 8) & 2047];    // prefetch next candidate (wraps harmlessly on last)
        KNN_DINS(knn_dist(pq, pm));
    }

    // tournament merge of the 8 partition lists (lanes p=0..7 of each query group)
    KNN_MERGE(1);
    KNN_MERGE(2);
    KNN_MERGE(4);
    // every lane now holds the global sorted top-16 distances; d15 = threshold

    const float t = d15;
    int* op = idxout + (((size_t)(b << 11) + q) << 4);
    float4 nxt2 = P[p];
    for (int it = 0; it < 256; ++it) {
        const float4 pm = nxt2;
        const int m = it * 8 + p;
        nxt2 = P[(m + 8) & 2047];
        const float d = knn_dist(pq, pm);
        if (d <= t) {
            const int pos = atomicAdd(&cnt[g], 1);
            if (pos < 16) op[pos] = m;   // order-scrambled: consumer is a max over the set
        }
    }
}

// ---------------- GEMM: TM(64|128) x 128o tile, BK=64, global_load_lds staging.
// Grid: x = o-blocks (fast-varying, shares B rows -> L2), y = m-blocks.
// POOL: fused per-column max/sum over m (atomics into global accumulators).
template<int TM, bool POOL>
__global__ __launch_bounds__(256) void gemm_tile(
    const _Float16* __restrict__ W, const _Float16* __restrict__ X,
    _Float16* __restrict__ Y, float* __restrict__ Y32,
    const float* __restrict__ bias, const _Float16* __restrict__ Res,
    int Kp, int ldX, int xoff, int ldY, int yoff, int Opad,
    int act, int biasPerBatch, int ldR, int roff, int Olimit,
    unsigned* __restrict__ pmaxG, float* __restrict__ psumG)
{
    constexpr int MI = TM / 32;                 // m-frags per wave
    __shared__ _Float16 SH[128 * 64 + TM * 64]; // As | Bs ; reused as output tile
    _Float16* As = SH;
    _Float16* Bs = SH + 128 * 64;

    const int tid  = threadIdx.x;
    const int lane = tid & 63, wave = tid >> 6;
    const int r = lane & 15, quad = lane >> 4;
    const int m_blk = blockIdx.y * TM, o_blk = blockIdx.x * 128;
    const int oh = (wave >> 1) * 64, mh = (wave & 1) * (TM / 2);

    f32x4 acc[4][MI];
#pragma unroll
    for (int a = 0; a < 4; ++a)
#pragma unroll
        for (int c = 0; c < MI; ++c) acc[a][c] = (f32x4){0.f, 0.f, 0.f, 0.f};

    const int srow  = wave * 8 + (lane >> 3);
    const int sslot = lane & 7;

    for (int k0 = 0; k0 < Kp; k0 += 64) {
        __syncthreads();
#pragma unroll
        for (int t = 0; t < 4; ++t) {           // A: 128 rows
            const int rowA = t * 32 + srow;
            const int gk = k0 + ((sslot ^ (rowA & 7)) << 3);
            const _Float16* gA = W + (size_t)(o_blk + rowA) * Kp + gk;
            __builtin_amdgcn_global_load_lds(
                (const __attribute__((address_space(1))) unsigned int*)gA,
                (__attribute__((address_space(3))) unsigned int*)(As + t * 2048 + wave * 512),
                16, 0, 0);
        }
#pragma unroll
        for (int t = 0; t < TM / 32; ++t) {     // B: TM rows
            const int rowB = t * 32 + srow;
            const int gk = k0 + ((sslot ^ (rowB & 7)) << 3);
            const _Float16* gB = X + (size_t)(m_blk + rowB) * ldX + xoff + gk;
            __builtin_amdgcn_global_load_lds(
                (const __attribute__((address_space(1))) unsigned int*)gB,
                (__attribute__((address_space(3))) unsigned int*)(Bs + t * 2048 + wave * 512),
                16, 0, 0);
        }
        __syncthreads();
#pragma unroll
        for (int ks = 0; ks < 2; ++ks) {
            f16x8 af[4], bf[MI];
#pragma unroll
            for (int oi = 0; oi < 4; ++oi) {
                const int row = oh + oi * 16 + r;
                const int slot = (ks * 4 + quad) ^ (row & 7);
                af[oi] = *(const f16x8*)(As + row * 64 + slot * 8);
            }
#pragma unroll
            for (int mi = 0; mi < MI; ++mi) {
                const int row = mh + mi * 16 + r;
                const int slot = (ks * 4 + quad) ^ (row & 7);
                bf[mi] = *(const f16x8*)(Bs + row * 64 + slot * 8);
            }
#pragma unroll
            for (int oi = 0; oi < 4; ++oi)
#pragma unroll
                for (int mi = 0; mi < MI; ++mi)
                    acc[oi][mi] = __builtin_amdgcn_mfma_f32_16x16x32_f16(af[oi], bf[mi], acc[oi][mi], 0, 0, 0);
        }
    }

    const int bb = biasPerBatch ? (m_blk >> 11) * Opad : 0;
    __syncthreads();   // done reading As/Bs; SH is reusable

    if (Y32) {
        // f32 path: store transposed to (B, 50, N): Y32[(b*50+o)*2048 + n], o < Olimit
#pragma unroll
        for (int oi = 0; oi < 4; ++oi) {
            const int og = o_blk + oh + oi * 16 + quad * 4;
            const f32x4 bv = *(const f32x4*)(bias + bb + og);
#pragma unroll
            for (int mi = 0; mi < MI; ++mi) {
                const int m = m_blk + mh + mi * 16 + r;
                const int bidx = m >> 11, n = m & 2047;
                f32x4 v = acc[oi][mi] + bv;
#pragma unroll
                for (int j = 0; j < 4; ++j) {
                    float x = v[j];
                    if (act == 1)      x = (x > 0.f) ? x : 0.0f;
                    else if (act == 2) x = (x > 0.f) ? x : 0.2f * x;
                    const int o = og + j;
                    if (o < Olimit)
                        Y32[((size_t)(bidx * 50 + o) << 11) + n] = x;
                }
            }
        }
        return;
    }

    // f16 path: stage [TM][128] tile in LDS (XOR-swizzled), then coalesced writeback
    float cmax[4][4], csum[4][4];
    if (POOL) {
#pragma unroll
        for (int a = 0; a < 4; ++a)
#pragma unroll
            for (int j = 0; j < 4; ++j) { cmax[a][j] = -3.4e38f; csum[a][j] = 0.f; }
    }
    _Float16* OT = SH;
#pragma unroll
    for (int oi = 0; oi < 4; ++oi) {
        const int ol = oh + oi * 16 + quad * 4;       // local o (0..127), 4-aligned
        const f32x4 bv = *(const f32x4*)(bias + bb + o_blk + ol);
#pragma unroll
        for (int mi = 0; mi < MI; ++mi) {
            const int row = mh + mi * 16 + r;         // local m
            f32x4 v = acc[oi][mi] + bv;
            if (Res) {
                f16x4 rr = *(const f16x4*)(Res + (size_t)(m_blk + row) * ldR + roff + o_blk + ol);
#pragma unroll
                for (int j = 0; j < 4; ++j) v[j] += (float)rr[j];
            }
            f16x4 ov;
#pragma unroll
            for (int j = 0; j < 4; ++j) {
                float x = v[j];
                if (act == 1)      x = (x > 0.f) ? x : 0.0f;
                else if (act == 2) x = (x > 0.f) ? x : 0.2f * x;
                ov[j] = (_Float16)x;
                if (POOL) { cmax[oi][j] = fmaxf(cmax[oi][j], x); csum[oi][j] += x; }
            }
            const int s = ((ol >> 2) ^ (row & 31)) << 2;   // swizzled 8B slot
            *(f16x4*)(OT + row * 128 + s) = ov;
        }
    }

    if (POOL) {
        // reduce over the 16 r-lanes of each quad group, then atomics from lane r==0
#pragma unroll
        for (int mask = 1; mask <= 8; mask <<= 1) {
#pragma unroll
            for (int a = 0; a < 4; ++a)
#pragma unroll
                for (int j = 0; j < 4; ++j) {
                    cmax[a][j] = fmaxf(cmax[a][j], __shfl_xor(cmax[a][j], mask));
                    csum[a][j] += __shfl_xor(csum[a][j], mask);
                }
        }
        if (r == 0) {
            const int bidx = m_blk >> 11;
#pragma unroll
            for (int a = 0; a < 4; ++a)
#pragma unroll
                for (int j = 0; j < 4; ++j) {
                    const int o = o_blk + oh + a * 16 + quad * 4 + j;
                    atomicMax(&pmaxG[(bidx << 10) + o], fmap(cmax[a][j]));
                    atomicAdd(&psumG[(bidx << 10) + o], csum[a][j]);
                }
        }
    }

    __syncthreads();
#pragma unroll
    for (int it2 = 0; it2 < TM / 16; ++it2) {
        const int row = it2 * 16 + (tid >> 4);
        const int c = tid & 15;                        // 8 f16 per lane, contiguous
        const int s0 = ((c * 2) ^ (row & 31)) << 2;
        const int s1 = ((c * 2 + 1) ^ (row & 31)) << 2;
        f16x4 a = *(const f16x4*)(OT + row * 128 + s0);
        f16x4 b2 = *(const f16x4*)(OT + row * 128 + s1);
        f16x8 o8;
        o8[0] = a[0]; o8[1] = a[1]; o8[2] = a[2]; o8[3] = a[3];
        o8[4] = b2[0]; o8[5] = b2[1]; o8[6] = b2[2]; o8[7] = b2[3];
        *(f16x8*)(Y + (size_t)(m_blk + row) * ldY + yoff + o_blk + c * 8) = o8;
    }
}

// ---------------- neighbor gather + channel max (relu outputs => ushort-monotonic f16 bits) ----------------
typedef short s16x8 __attribute__((ext_vector_type(8)));
__global__ __launch_bounds__(256) void gather_max_kernel(
    const short* __restrict__ T, const int* __restrict__ idx, short* __restrict__ Mo)
{
    const int tid = threadIdx.x;
    const int p = blockIdx.x * 16 + (tid >> 4);
    const int l = tid & 15;
    const int b = p >> 11;
    const int* ip = idx + (size_t)p * 16;
    size_t row = (size_t)((b << 11) + ip[0]);
    s16x8 cur = *(const s16x8*)(T + row * 128 + l * 8);
    unsigned short best[8];
#pragma unroll
    for (int e = 0; e < 8; ++e) best[e] = (unsigned short)cur[e];
#pragma unroll
    for (int j = 1; j < 16; ++j) {
        row = (size_t)((b << 11) + ip[j]);
        s16x8 v = *(const s16x8*)(T + row * 128 + l * 8);
#pragma unroll
        for (int e = 0; e < 8; ++e) {
            unsigned short u = (unsigned short)v[e];
            if (u > best[e]) best[e] = u;
        }
    }
    s16x8 ov;
#pragma unroll
    for (int e = 0; e < 8; ++e) ov[e] = (short)best[e];
    *(s16x8*)(Mo + (size_t)p * 128 + l * 8) = ov;
}

// ---------------- per-batch constant vector for Wc1 (reads fused pool accumulators) ----------------
__global__ __launch_bounds__(256) void cvec_kernel(
    const float* __restrict__ label, const float* __restrict__ Wl, const float* __restrict__ gl, const float* __restrict__ bl,
    const float* __restrict__ Wc1, const float* __restrict__ bc1, const float* __restrict__ gc1, const float* __restrict__ bb1,
    const unsigned* __restrict__ pmax, const float* __restrict__ psum, float* __restrict__ cvec)
{
    __shared__ float v[2112];
    __shared__ float red[256];
    const int b = blockIdx.x, og = blockIdx.y, tid = threadIdx.x;
    for (int i = tid; i < 1024; i += 256) {
        v[i] = funmap(pmax[((size_t)b << 10) + i]);
        v[1024 + i] = psum[((size_t)b << 10) + i] * (1.f / 2048.f);
    }
    if (tid < 64) {
        float s = 0.f;
        for (int i = 0; i < 16; ++i) s += Wl[tid * 16 + i] * label[b * 16 + i];
        s = gl[tid] * s + bl[tid];
        v[2048 + tid] = (s > 0.f) ? s : 0.2f * s;
    }
    __syncthreads();
    const int o = og * 64 + (tid >> 2), part = tid & 3;
    const float* wrow = Wc1 + (size_t)o * 3136 + 1024 + part * 528;
    float s = 0.f;
    for (int j = 0; j < 528; ++j) s += wrow[j] * v[part * 528 + j];
    red[tid] = s;
    __syncthreads();
    if (part == 0) {
        float tot = red[tid] + red[tid + 1] + red[tid + 2] + red[tid + 3];
        cvec[((size_t)b << 9) + o] = gc1[o] * (tot + bc1[o]) + bb1[o];
    }
}

// ---------------- launch ----------------
extern "C" void kernel_launch(void* const* d_in, const int* in_sizes, int n_in,
                              void* d_out, int out_size, void* d_ws, size_t ws_size,
                              hipStream_t stream)
{
    (void)in_sizes; (void)n_in; (void)out_size; (void)ws_size;
    const float* points = (const float*)d_in[0];
    const float* label  = (const float*)d_in[1];
    const float* We1 = (const float*)d_in[2];
    const float* ge1 = (const float*)d_in[3];
    const float* be1 = (const float*)d_in[4];
    const float* We2 = (const float*)d_in[5];
    const float* ge2 = (const float*)d_in[6];
    const float* be2 = (const float*)d_in[7];
    const float* W1  = (const float*)d_in[8];
    const float* g1  = (const float*)d_in[9];
    const float* b1  = (const float*)d_in[10];
    const float* W2  = (const float*)d_in[11];
    const float* g2  = (const float*)d_in[12];
    const float* b2  = (const float*)d_in[13];
    const float* Wf  = (const float*)d_in[14];
    const float* gf  = (const float*)d_in[15];
    const float* bfv = (const float*)d_in[16];
    const float* Wl  = (const float*)d_in[17];
    const float* gl  = (const float*)d_in[18];
    const float* bl  = (const float*)d_in[19];
    const float* Wc1 = (const float*)d_in[20];
    const float* bc1 = (const float*)d_in[21];
    const float* gc1 = (const float*)d_in[22];
    const float* bb1 = (const float*)d_in[23];
    const float* Wc2 = (const float*)d_in[24];
    const float* bc2 = (const float*)d_in[25];
    const float* gc2 = (const float*)d_in[26];
    const float* bb2 = (const float*)d_in[27];
    const float* Wc3 = (const float*)d_in[28];
    const float* bc3 = (const float*)d_in[29];

    char* ws = (char*)d_ws;
    _Float16* hT  = (_Float16*)(ws + OFF_HT);
    _Float16* tT  = (_Float16*)(ws + OFF_TT);
    _Float16* mT  = (_Float16*)(ws + OFF_MT);
    _Float16* xct = (_Float16*)(ws + OFF_XCAT);
    _Float16* xf  = (_Float16*)(ws + OFF_XF);
    _Float16* c1  = (_Float16*)(ws + OFF_C1);
    _Float16* c2  = (_Float16*)(ws + OFF_C2);
    int*      idx = (int*)     (ws + OFF_IDX);
    _Float16* x0  = (_Float16*)(ws + OFF_X0);

    _Float16* wE1 = (_Float16*)(ws + OFF_WE1);
    _Float16* wE2 = (_Float16*)(ws + OFF_WE2);
    _Float16* w1f = (_Float16*)(ws + OFF_W1);
    _Float16* w2f = (_Float16*)(ws + OFF_W2);
    _Float16* wF  = (_Float16*)(ws + OFF_WF);
    _Float16* wC1 = (_Float16*)(ws + OFF_WC1);
    _Float16* wC2 = (_Float16*)(ws + OFF_WC2);
    _Float16* wC3 = (_Float16*)(ws + OFF_WC3);
    float* bC2 = (float*)(ws + OFF_BC2);
    float* bC3 = (float*)(ws + OFF_BC3);
    float* cv  = (float*)(ws + OFF_CVEC);
    unsigned* pmx = (unsigned*)(ws + OFF_PMAX);
    float*    psm = (float*)   (ws + OFF_PSUM);

    // prep (weights + biases + x0 + pool-acc init, one launch)
    fold_all_kernel<<<dim3(4962), 256, 0, stream>>>(We1, ge1, We2, ge2, W1, g1, W2, g2,
                                                    Wf, gf, Wc1, gc1, Wc2, gc2, Wc3,
                                                    gc2, bc2, bb2, bc3, points, ws);
    knn_kernel<<<dim3(BB, NN / 32), 256, 0, stream>>>(points, idx);

    // e1: x0(Mx64,pad) -> tT(Mx128), relu
    gemm_tile<64, false><<<dim3(1, 512), 256, 0, stream>>>(wE1, x0, tT, nullptr, be1, nullptr, 64, 64, 0, 128, 0, 128, 1, 0, 0, 0, 128, nullptr, nullptr);
    // e2: tT -> hT, relu
    gemm_tile<64, false><<<dim3(1, 512), 256, 0, stream>>>(wE2, tT, hT, nullptr, be2, nullptr, 128, 128, 0, 128, 0, 128, 1, 0, 0, 0, 128, nullptr, nullptr);

    for (int i = 0; i < 3; ++i) {
        const _Float16* hin = (i == 0) ? hT : xct;
        int ldH  = (i == 0) ? 128 : 384;
        int offH = (i == 0) ? 0 : (i - 1) * 128;
        // t = relu(bn(W1 h))
        gemm_tile<64, false><<<dim3(1, 512), 256, 0, stream>>>(w1f + (size_t)i * 16384, hin, tT, nullptr, b1 + i * 128, nullptr,
                                                               128, ldH, offH, 128, 0, 128, 1, 0, 0, 0, 128, nullptr, nullptr);
        // m = neighbor max
        gather_max_kernel<<<dim3(MM / 16), 256, 0, stream>>>((const short*)tT, idx, (short*)mT);
        // h' = relu(bn(W2 m) + h) -> xcat slice i
        gemm_tile<64, false><<<dim3(1, 512), 256, 0, stream>>>(w2f + (size_t)i * 16384, mT, xct, nullptr, b2 + i * 128, hin,
                                                               128, 128, 0, 384, i * 128, 128, 1, 0, ldH, offH, 128, nullptr, nullptr);
    }

    // xf = leaky(bn(Wf xcat)) with fused max/mean pooling accumulation
    gemm_tile<128, true><<<dim3(8, 256), 256, 0, stream>>>(wF, xct, xf, nullptr, bfv, nullptr, 384, 384, 0, 1024, 0, 1024, 2, 0, 0, 0, 1024, pmx, psm);

    // per-batch classifier constant (consumes fused pool accumulators)
    cvec_kernel<<<dim3(BB, 8), 256, 0, stream>>>(label, Wl, gl, bl, Wc1, bc1, gc1, bb1, pmx, psm, cv);

    // c1 = relu(gc1*Wc1[:, :1024] xf + cvec[b])
    gemm_tile<128, false><<<dim3(4, 256), 256, 0, stream>>>(wC1, xf, c1, nullptr, cv, nullptr, 1024, 1024, 0, 512, 0, 512, 1, 1, 0, 0, 512, nullptr, nullptr);
    // c2 = relu(bn(Wc2 c1 + bc2))
    gemm_tile<128, false><<<dim3(2, 256), 256, 0, stream>>>(wC2, c1, c2, nullptr, bC2, nullptr, 512, 512, 0, 256, 0, 256, 1, 0, 0, 0, 256, nullptr, nullptr);
    // c3 = Wc3 c2 + bc3 (no act), f32, stored transposed directly to (B,50,N) output
    gemm_tile<128, false><<<dim3(1, 256), 256, 0, stream>>>(wC3, c2, nullptr, (float*)d_out, bC3, nullptr, 256, 256, 0, 0, 0, 128, 0, 0, 0, 0, 50, nullptr, nullptr);
}

// Round 12
// 445.754 us; speedup vs baseline: 1.0651x; 1.0651x over previous
//
#include <hip/hip_runtime.h>
#include <cstdint>
#include <cstddef>

#define DEVINL __device__ __forceinline__

typedef float    f32x4 __attribute__((ext_vector_type(4)));
typedef _Float16 f16x8 __attribute__((ext_vector_type(8)));
typedef _Float16 f16x4 __attribute__((ext_vector_type(4)));

// ---------------- constants ----------------
constexpr int BB = 16, NN = 2048, MM = 32768;

// ---------------- ws layout (bytes) ----------------
constexpr size_t OFF_WE1 = 0;                           // 128x64 f16 (Kp padded 6->64)
constexpr size_t OFF_WE2 = OFF_WE1 + 128 * 64 * 2;
constexpr size_t OFF_W1  = OFF_WE2 + 128 * 128 * 2;
constexpr size_t OFF_W2  = OFF_W1  + 3 * 128 * 128 * 2;
constexpr size_t OFF_WF  = OFF_W2  + 3 * 128 * 128 * 2;
constexpr size_t OFF_WC1 = OFF_WF  + 1024 * 384 * 2;
constexpr size_t OFF_WC2 = OFF_WC1 + 512 * 1024 * 2;
constexpr size_t OFF_WC3 = OFF_WC2 + 256 * 512 * 2;     // 128x256 (Opad 50->128)
constexpr size_t OFF_BC2 = OFF_WC3 + 128 * 256 * 2;     // 256 f32
constexpr size_t OFF_BC3 = OFF_BC2 + 256 * 4;           // 128 f32
constexpr size_t OFF_CVEC= OFF_BC3 + 128 * 4;           // 16x512 f32
constexpr size_t OFF_PMAX= OFF_CVEC+ 16 * 512 * 4;      // 16x1024 mapped-uint (atomic max)
constexpr size_t OFF_PSUM= OFF_PMAX+ 16 * 1024 * 4;     // 16x1024 f32 (atomic add)
constexpr size_t OFF_IDX = OFF_PSUM+ 16 * 1024 * 4;
constexpr size_t OFF_R1  = 8ull << 20;                  // > OFF_IDX + 2MB
constexpr size_t OFF_X0  = OFF_R1;                      // 4MB  (M x 64 f16, k-padded)
constexpr size_t OFF_HT  = OFF_R1 + (4ull  << 20);      // 8MB  (M x 128 f16)
constexpr size_t OFF_TT  = OFF_R1 + (12ull << 20);      // 8MB
constexpr size_t OFF_MT  = OFF_R1 + (20ull << 20);      // 8MB
constexpr size_t OFF_C1  = OFF_R1;                      // 32MB (M x 512 f16), aliases x0/h/t/m (dead)
constexpr size_t OFF_XCAT= OFF_R1 + (32ull << 20);      // 24MB (M x 384 f16)
constexpr size_t OFF_C2  = OFF_XCAT;                    // 16MB (M x 256 f16), aliases xcat (dead)
constexpr size_t OFF_XF  = OFF_XCAT + (24ull << 20);    // 64MB (M x 1024 f16)

DEVINL unsigned fmap(float f) {            // order-preserving float->uint
    unsigned u = __float_as_uint(f);
    return (u & 0x80000000u) ? ~u : (u | 0x80000000u);
}
DEVINL float funmap(unsigned u) {
    return (u & 0x80000000u) ? __uint_as_float(u & 0x7FFFFFFFu) : __uint_as_float(~u);
}

// ---------------- fold-all: weights (f16, BN-folded), biases, x0 prep, pool-acc init ----------------
__global__ __launch_bounds__(256) void fold_all_kernel(
    const float* We1, const float* ge1, const float* We2, const float* ge2,
    const float* W1,  const float* g1,  const float* W2,  const float* g2,
    const float* Wf,  const float* gf,  const float* Wc1, const float* gc1,
    const float* Wc2, const float* gc2, const float* Wc3,
    const float* gc2b, const float* bc2, const float* bb2, const float* bc3,
    const float* pts, char* ws)
{
    const int bid = blockIdx.x;
    const int tid = threadIdx.x;

    if (bid == 4704) {
        ((float*)(ws + OFF_BC2))[tid] = gc2b[tid] * bc2[tid] + bb2[tid];
        return;
    }
    if (bid == 4705) {
        if (tid < 128) ((float*)(ws + OFF_BC3))[tid] = (tid < 50) ? bc3[tid] : 0.f;
        return;
    }
    if (bid >= 4834) {           // pool accumulator init: pmax (mapped) = 0, psum = 0
        int f = (bid - 4834) * 256 + tid;
        if (f < 16384) ((unsigned*)(ws + OFF_PMAX))[f] = 0u;
        else           ((float*)   (ws + OFF_PSUM))[f - 16384] = 0.f;
        return;
    }
    if (bid >= 4706) {           // x0 prep: (B,6,N) f32 -> (M x 64) f16 K-contig, zero pad
        int m = (bid - 4706) * 256 + tid;
        int b = m >> 11, n = m & 2047;
        const float* ps = pts + (size_t)b * 6 * 2048 + n;
        _Float16 tmp[64];
#pragma unroll
        for (int c = 0; c < 64; ++c) tmp[c] = (_Float16)0.f;
#pragma unroll
        for (int c = 0; c < 6; ++c) tmp[c] = (_Float16)ps[(size_t)c << 11];
        _Float16* dst = (_Float16*)(ws + OFF_X0) + (size_t)m * 64;
#pragma unroll
        for (int v = 0; v < 8; ++v) *(f16x8*)(dst + v * 8) = *(const f16x8*)(tmp + v * 8);
        return;
    }

    int id, base;
    if      (bid < 32)   { id = 0;  base = 0;    }
    else if (bid < 96)   { id = 1;  base = 32;   }
    else if (bid < 160)  { id = 2;  base = 96;   }
    else if (bid < 224)  { id = 3;  base = 160;  }
    else if (bid < 288)  { id = 4;  base = 224;  }
    else if (bid < 352)  { id = 5;  base = 288;  }
    else if (bid < 416)  { id = 6;  base = 352;  }
    else if (bid < 480)  { id = 7;  base = 416;  }
    else if (bid < 2016) { id = 8;  base = 480;  }
    else if (bid < 4064) { id = 9;  base = 2016; }
    else if (bid < 4576) { id = 10; base = 4064; }
    else                 { id = 11; base = 4576; }

    const float* src = nullptr; const float* g = nullptr; _Float16* dst = nullptr;
    int O = 0, K = 0, lds = 0, Kp = 0;
    switch (id) {
        case 0:  src = We1; g = ge1; O = 128; K = 6;    lds = 6;    Kp = 64;   dst = (_Float16*)(ws + OFF_WE1); break;
        case 1:  src = We2; g = ge2; O = 128; K = 128;  lds = 128;  Kp = 128;  dst = (_Float16*)(ws + OFF_WE2); break;
        case 2: case 3: case 4: {
            int i = id - 2;
            src = W1 + (size_t)i * 16384; g = g1 + i * 128; O = 128; K = 128; lds = 128; Kp = 128;
            dst = (_Float16*)(ws + OFF_W1) + (size_t)i * 16384; break; }
        case 5: case 6: case 7: {
            int i = id - 5;
            src = W2 + (size_t)i * 16384; g = g2 + i * 128; O = 128; K = 128; lds = 128; Kp = 128;
            dst = (_Float16*)(ws + OFF_W2) + (size_t)i * 16384; break; }
        case 8:  src = Wf;  g = gf;  O = 1024; K = 384;  lds = 384;  Kp = 384;  dst = (_Float16*)(ws + OFF_WF);  break;
        case 9:  src = Wc1; g = gc1; O = 512;  K = 1024; lds = 3136; Kp = 1024; dst = (_Float16*)(ws + OFF_WC1); break;
        case 10: src = Wc2; g = gc2; O = 256;  K = 512;  lds = 512;  Kp = 512;  dst = (_Float16*)(ws + OFF_WC2); break;
        default: src = Wc3; g = nullptr; O = 50; K = 256; lds = 256; Kp = 256;  dst = (_Float16*)(ws + OFF_WC3); break;
    }
    int e = (bid - base) * 256 + tid;
    int o = e / Kp, k = e - o * Kp;
    float v = 0.f;
    if (o < O && k < K) {
        v = src[(size_t)o * lds + k];
        if (g) v *= g[o];
    }
    dst[e] = (_Float16)v;
}

// ---------------- KNN: fused select+collect, in-wave bitonic tournament merge ----------------
DEVINL float knn_dist(const float4 pq, const float4 pm) {
    float t = pq.x * pm.x;
    t = fmaf(pq.y, pm.y, t);
    t = fmaf(pq.z, pm.z, t);
    return fmaf(-2.f, t, pm.w);
}

#define KNN_DINS(X) do { \
    const float x_ = (X); \
    d15 = __builtin_amdgcn_fmed3f(x_, d14, d15); \
    d14 = __builtin_amdgcn_fmed3f(x_, d13, d14); \
    d13 = __builtin_amdgcn_fmed3f(x_, d12, d13); \
    d12 = __builtin_amdgcn_fmed3f(x_, d11, d12); \
    d11 = __builtin_amdgcn_fmed3f(x_, d10, d11); \
    d10 = __builtin_amdgcn_fmed3f(x_, d9,  d10); \
    d9  = __builtin_amdgcn_fmed3f(x_, d8,  d9);  \
    d8  = __builtin_amdgcn_fmed3f(x_, d7,  d8);  \
    d7  = __builtin_amdgcn_fmed3f(x_, d6,  d7);  \
    d6  = __builtin_amdgcn_fmed3f(x_, d5,  d6);  \
    d5  = __builtin_amdgcn_fmed3f(x_, d4,  d5);  \
    d4  = __builtin_amdgcn_fmed3f(x_, d3,  d4);  \
    d3  = __builtin_amdgcn_fmed3f(x_, d2,  d3);  \
    d2  = __builtin_amdgcn_fmed3f(x_, d1,  d2);  \
    d1  = __builtin_amdgcn_fmed3f(x_, d0,  d1);  \
    d0  = __builtin_amdgcn_fmed3f(x_, -3.4e38f, d0); \
} while (0)

#define KNN_CE(A, B) { const float lo_ = fminf(A, B), hi_ = fmaxf(A, B); A = lo_; B = hi_; }

#define KNN_MERGE(OFF) do { \
    const float n0  = __shfl_xor(d0,  OFF), n1  = __shfl_xor(d1,  OFF), \
                n2  = __shfl_xor(d2,  OFF), n3  = __shfl_xor(d3,  OFF), \
                n4  = __shfl_xor(d4,  OFF), n5  = __shfl_xor(d5,  OFF), \
                n6  = __shfl_xor(d6,  OFF), n7  = __shfl_xor(d7,  OFF), \
                n8  = __shfl_xor(d8,  OFF), n9  = __shfl_xor(d9,  OFF), \
                n10 = __shfl_xor(d10, OFF), n11 = __shfl_xor(d11, OFF), \
                n12 = __shfl_xor(d12, OFF), n13 = __shfl_xor(d13, OFF), \
                n14 = __shfl_xor(d14, OFF), n15 = __shfl_xor(d15, OFF); \
    d0  = fminf(d0,  n15); d1  = fminf(d1,  n14); d2  = fminf(d2,  n13); d3  = fminf(d3,  n12); \
    d4  = fminf(d4,  n11); d5  = fminf(d5,  n10); d6  = fminf(d6,  n9);  d7  = fminf(d7,  n8);  \
    d8  = fminf(d8,  n7);  d9  = fminf(d9,  n6);  d10 = fminf(d10, n5);  d11 = fminf(d11, n4);  \
    d12 = fminf(d12, n3);  d13 = fminf(d13, n2);  d14 = fminf(d14, n1);  d15 = fminf(d15, n0);  \
    KNN_CE(d0, d8)  KNN_CE(d1, d9)  KNN_CE(d2, d10) KNN_CE(d3, d11) \
    KNN_CE(d4, d12) KNN_CE(d5, d13) KNN_CE(d6, d14) KNN_CE(d7, d15) \
    KNN_CE(d0, d4)  KNN_CE(d1, d5)  KNN_CE(d2, d6)  KNN_CE(d3, d7)  \
    KNN_CE(d8, d12) KNN_CE(d9, d13) KNN_CE(d10,d14) KNN_CE(d11,d15) \
    KNN_CE(d0, d2)  KNN_CE(d1, d3)  KNN_CE(d4, d6)  KNN_CE(d5, d7)  \
    KNN_CE(d8, d10) KNN_CE(d9, d11) KNN_CE(d12,d14) KNN_CE(d13,d15) \
    KNN_CE(d0, d1)  KNN_CE(d2, d3)  KNN_CE(d4, d5)  KNN_CE(d6, d7)  \
    KNN_CE(d8, d9)  KNN_CE(d10,d11) KNN_CE(d12,d13) KNN_CE(d14,d15) \
} while (0)

__global__ __launch_bounds__(256) void knn_kernel(const float* __restrict__ pts, int* __restrict__ idxout)
{
    __shared__ float4 P[2048];       // 32KB, stays intact for the rescan
    __shared__ int    cnt[32];
    const int tid = threadIdx.x;
    const int b = blockIdx.x;
    const float* pb = pts + (size_t)b * 6 * 2048;
    for (int i = tid; i < 2048; i += 256) {
        float x = pb[i];
        float y = pb[2048 + i];
        float z = pb[4096 + i];
        P[i] = make_float4(x, y, z, x * x + y * y + z * z);
    }
    if (tid < 32) cnt[tid] = 0;
    __syncthreads();

    const int p = tid & 7;          // candidate partition (m == 8*it + p)
    const int g = tid >> 3;         // query within block (0..31)
    const int q = blockIdx.y * 32 + g;
    const float4 pq = P[q];

    float d0 = 3.4e38f, d1 = 3.4e38f, d2 = 3.4e38f, d3 = 3.4e38f,
          d4 = 3.4e38f, d5 = 3.4e38f, d6 = 3.4e38f, d7 = 3.4e38f,
          d8 = 3.4e38f, d9 = 3.4e38f, d10 = 3.4e38f, d11 = 3.4e38f,
          d12 = 3.4e38f, d13 = 3.4e38f, d14 = 3.4e38f, d15 = 3.4e38f;

    float4 nxt = P[p];
#pragma unroll 2
    for (int it = 0; it < 256; ++it) {
        const float4 pm = nxt;
        const int m = it * 8 + p;
        nxt = P[(m + 8) & 2047];    // prefetch next candidate (wraps harmlessly on last)
        KNN_DINS(knn_dist(pq, pm));
    }

    // tournament merge of the 8 partition lists (lanes p=0..7 of each query group)
    KNN_MERGE(1);
    KNN_MERGE(2);
    KNN_MERGE(4);
    // every lane now holds the global sorted top-16 distances; d15 = threshold

    const float t = d15;
    int* op = idxout + (((size_t)(b << 11) + q) << 4);
    float4 nxt2 = P[p];
    for (int it = 0; it < 256; ++it) {
        const float4 pm = nxt2;
        const int m = it * 8 + p;
        nxt2 = P[(m + 8) & 2047];
        const float d = knn_dist(pq, pm);
        if (d <= t) {
            const int pos = atomicAdd(&cnt[g], 1);
            if (pos < 16) op[pos] = m;   // order-scrambled: consumer is a max over the set
        }
    }
}

// ---------------- GEMM: TM(64|128) x 128o tile, BK=64, global_load_lds staging.
// Grid: x = m-blocks (fast-varying; weights reused via L2), y = o-blocks.
// POOL: fused per-column max/sum over m (LDS cross-wave combine -> one atomic pair/o/block).
template<int TM, bool POOL>
__global__ __launch_bounds__(256) void gemm_tile(
    const _Float16* __restrict__ W, const _Float16* __restrict__ X,
    _Float16* __restrict__ Y, float* __restrict__ Y32,
    const float* __restrict__ bias, const _Float16* __restrict__ Res,
    int Kp, int ldX, int xoff, int ldY, int yoff, int Opad,
    int act, int biasPerBatch, int ldR, int roff, int Olimit,
    unsigned* __restrict__ pmaxG, float* __restrict__ psumG)
{
    constexpr int MI = TM / 32;                 // m-frags per wave
    __shared__ _Float16 SH[128 * 64 + TM * 64]; // As | Bs ; reused as output tile
    __shared__ float PM[POOL ? 256 : 1];        // cross-wave pool combine
    _Float16* As = SH;
    _Float16* Bs = SH + 128 * 64;

    const int tid  = threadIdx.x;
    const int lane = tid & 63, wave = tid >> 6;
    const int r = lane & 15, quad = lane >> 4;
    const int m_blk = blockIdx.x * TM, o_blk = blockIdx.y * 128;
    const int oh = (wave >> 1) * 64, mh = (wave & 1) * (TM / 2);

    f32x4 acc[4][MI];
#pragma unroll
    for (int a = 0; a < 4; ++a)
#pragma unroll
        for (int c = 0; c < MI; ++c) acc[a][c] = (f32x4){0.f, 0.f, 0.f, 0.f};

    const int srow  = wave * 8 + (lane >> 3);
    const int sslot = lane & 7;

    for (int k0 = 0; k0 < Kp; k0 += 64) {
        __syncthreads();
#pragma unroll
        for (int t = 0; t < 4; ++t) {           // A: 128 rows
            const int rowA = t * 32 + srow;
            const int gk = k0 + ((sslot ^ (rowA & 7)) << 3);
            const _Float16* gA = W + (size_t)(o_blk + rowA) * Kp + gk;
            __builtin_amdgcn_global_load_lds(
                (const __attribute__((address_space(1))) unsigned int*)gA,
                (__attribute__((address_space(3))) unsigned int*)(As + t * 2048 + wave * 512),
                16, 0, 0);
        }
#pragma unroll
        for (int t = 0; t < TM / 32; ++t) {     // B: TM rows
            const int rowB = t * 32 + srow;
            const int gk = k0 + ((sslot ^ (rowB & 7)) << 3);
            const _Float16* gB = X + (size_t)(m_blk + rowB) * ldX + xoff + gk;
            __builtin_amdgcn_global_load_lds(
                (const __attribute__((address_space(1))) unsigned int*)gB,
                (__attribute__((address_space(3))) unsigned int*)(Bs + t * 2048 + wave * 512),
                16, 0, 0);
        }
        __syncthreads();
#pragma unroll
        for (int ks = 0; ks < 2; ++ks) {
            f16x8 af[4], bf[MI];
#pragma unroll
            for (int oi = 0; oi < 4; ++oi) {
                const int row = oh + oi * 16 + r;
                const int slot = (ks * 4 + quad) ^ (row & 7);
                af[oi] = *(const f16x8*)(As + row * 64 + slot * 8);
            }
#pragma unroll
            for (int mi = 0; mi < MI; ++mi) {
                const int row = mh + mi * 16 + r;
                const int slot = (ks * 4 + quad) ^ (row & 7);
                bf[mi] = *(const f16x8*)(Bs + row * 64 + slot * 8);
            }
#pragma unroll
            for (int oi = 0; oi < 4; ++oi)
#pragma unroll
                for (int mi = 0; mi < MI; ++mi)
                    acc[oi][mi] = __builtin_amdgcn_mfma_f32_16x16x32_f16(af[oi], bf[mi], acc[oi][mi], 0, 0, 0);
        }
    }

    const int bb = biasPerBatch ? (m_blk >> 11) * Opad : 0;
    __syncthreads();   // done reading As/Bs; SH is reusable

    if (Y32) {
        // f32 path: store transposed to (B, 50, N): Y32[(b*50+o)*2048 + n], o < Olimit
#pragma unroll
        for (int oi = 0; oi < 4; ++oi) {
            const int og = o_blk + oh + oi * 16 + quad * 4;
            const f32x4 bv = *(const f32x4*)(bias + bb + og);
#pragma unroll
            for (int mi = 0; mi < MI; ++mi) {
                const int m = m_blk + mh + mi * 16 + r;
                const int bidx = m >> 11, n = m & 2047;
                f32x4 v = acc[oi][mi] + bv;
#pragma unroll
                for (int j = 0; j < 4; ++j) {
                    float x = v[j];
                    if (act == 1)      x = (x > 0.f) ? x : 0.0f;
                    else if (act == 2) x = (x > 0.f) ? x : 0.2f * x;
                    const int o = og + j;
                    if (o < Olimit)
                        Y32[((size_t)(bidx * 50 + o) << 11) + n] = x;
                }
            }
        }
        return;
    }

    // f16 path: stage [TM][128] tile in LDS (XOR-swizzled), then coalesced writeback
    float cmax[4][4], csum[4][4];
    if (POOL) {
#pragma unroll
        for (int a = 0; a < 4; ++a)
#pragma unroll
            for (int j = 0; j < 4; ++j) { cmax[a][j] = -3.4e38f; csum[a][j] = 0.f; }
    }
    _Float16* OT = SH;
#pragma unroll
    for (int oi = 0; oi < 4; ++oi) {
        const int ol = oh + oi * 16 + quad * 4;       // local o (0..127), 4-aligned
        const f32x4 bv = *(const f32x4*)(bias + bb + o_blk + ol);
#pragma unroll
        for (int mi = 0; mi < MI; ++mi) {
            const int row = mh + mi * 16 + r;         // local m
            f32x4 v = acc[oi][mi] + bv;
            if (Res) {
                f16x4 rr = *(const f16x4*)(Res + (size_t)(m_blk + row) * ldR + roff + o_blk + ol);
#pragma unroll
                for (int j = 0; j < 4; ++j) v[j] += (float)rr[j];
            }
            f16x4 ov;
#pragma unroll
            for (int j = 0; j < 4; ++j) {
                float x = v[j];
                if (act == 1)      x = (x > 0.f) ? x : 0.0f;
                else if (act == 2) x = (x > 0.f) ? x : 0.2f * x;
                ov[j] = (_Float16)x;
                if (POOL) { cmax[oi][j] = fmaxf(cmax[oi][j], x); csum[oi][j] += x; }
            }
            const int s = ((ol >> 2) ^ (row & 31)) << 2;   // swizzled 8B slot
            *(f16x4*)(OT + row * 128 + s) = ov;
        }
    }

    if (POOL) {
        // reduce over the 16 r-lanes
#pragma unroll
        for (int mask = 1; mask <= 8; mask <<= 1) {
#pragma unroll
            for (int a = 0; a < 4; ++a)
#pragma unroll
                for (int j = 0; j < 4; ++j) {
                    cmax[a][j] = fmaxf(cmax[a][j], __shfl_xor(cmax[a][j], mask));
                    csum[a][j] += __shfl_xor(csum[a][j], mask);
                }
        }
        // cross-wave combine: waves {0,2} (mh=0) write, waves {1,3} (mh=64) merge+atomic
        if (r == 0 && (wave & 1) == 0) {
#pragma unroll
            for (int a = 0; a < 4; ++a)
#pragma unroll
                for (int j = 0; j < 4; ++j) {
                    const int ol = oh + a * 16 + quad * 4 + j;     // 0..127
                    PM[ol] = cmax[a][j];
                    PM[128 + ol] = csum[a][j];
                }
        }
        __syncthreads();
        if (r == 0 && (wave & 1) == 1) {
            const int bidx = m_blk >> 11;
#pragma unroll
            for (int a = 0; a < 4; ++a)
#pragma unroll
                for (int j = 0; j < 4; ++j) {
                    const int ol = oh + a * 16 + quad * 4 + j;
                    const int o = o_blk + ol;
                    atomicMax(&pmaxG[(bidx << 10) + o], fmap(fmaxf(cmax[a][j], PM[ol])));
                    atomicAdd(&psumG[(bidx << 10) + o], csum[a][j] + PM[128 + ol]);
                }
        }
    }

    __syncthreads();
#pragma unroll
    for (int it2 = 0; it2 < TM / 16; ++it2) {
        const int row = it2 * 16 + (tid >> 4);
        const int c = tid & 15;                        // 8 f16 per lane, contiguous
        const int s0 = ((c * 2) ^ (row & 31)) << 2;
        const int s1 = ((c * 2 + 1) ^ (row & 31)) << 2;
        f16x4 a = *(const f16x4*)(OT + row * 128 + s0);
        f16x4 b2 = *(const f16x4*)(OT + row * 128 + s1);
        f16x8 o8;
        o8[0] = a[0]; o8[1] = a[1]; o8[2] = a[2]; o8[3] = a[3];
        o8[4] = b2[0]; o8[5] = b2[1]; o8[6] = b2[2]; o8[7] = b2[3];
        *(f16x8*)(Y + (size_t)(m_blk + row) * ldY + yoff + o_blk + c * 8) = o8;
    }
}

// ---------------- neighbor gather + channel max (relu outputs => ushort-monotonic f16 bits) ----------------
typedef short s16x8 __attribute__((ext_vector_type(8)));
__global__ __launch_bounds__(256) void gather_max_kernel(
    const short* __restrict__ T, const int* __restrict__ idx, short* __restrict__ Mo)
{
    const int tid = threadIdx.x;
    const int p = blockIdx.x * 16 + (tid >> 4);
    const int l = tid & 15;
    const int b = p >> 11;
    const int* ip = idx + (size_t)p * 16;
    size_t row = (size_t)((b << 11) + ip[0]);
    s16x8 cur = *(const s16x8*)(T + row * 128 + l * 8);
    unsigned short best[8];
#pragma unroll
    for (int e = 0; e < 8; ++e) best[e] = (unsigned short)cur[e];
#pragma unroll
    for (int j = 1; j < 16; ++j) {
        row = (size_t)((b << 11) + ip[j]);
        s16x8 v = *(const s16x8*)(T + row * 128 + l * 8);
#pragma unroll
        for (int e = 0; e < 8; ++e) {
            unsigned short u = (unsigned short)v[e];
            if (u > best[e]) best[e] = u;
        }
    }
    s16x8 ov;
#pragma unroll
    for (int e = 0; e < 8; ++e) ov[e] = (short)best[e];
    *(s16x8*)(Mo + (size_t)p * 128 + l * 8) = ov;
}

// ---------------- per-batch constant vector for Wc1 (reads fused pool accumulators) ----------------
__global__ __launch_bounds__(256) void cvec_kernel(
    const float* __restrict__ label, const float* __restrict__ Wl, const float* __restrict__ gl, const float* __restrict__ bl,
    const float* __restrict__ Wc1, const float* __restrict__ bc1, const float* __restrict__ gc1, const float* __restrict__ bb1,
    const unsigned* __restrict__ pmax, const float* __restrict__ psum, float* __restrict__ cvec)
{
    __shared__ float v[2112];
    __shared__ float red[256];
    const int b = blockIdx.x, og = blockIdx.y, tid = threadIdx.x;
    for (int i = tid; i < 1024; i += 256) {
        v[i] = funmap(pmax[((size_t)b << 10) + i]);
        v[1024 + i] = psum[((size_t)b << 10) + i] * (1.f / 2048.f);
    }
    if (tid < 64) {
        float s = 0.f;
        for (int i = 0; i < 16; ++i) s += Wl[tid * 16 + i] * label[b * 16 + i];
        s = gl[tid] * s + bl[tid];
        v[2048 + tid] = (s > 0.f) ? s : 0.2f * s;
    }
    __syncthreads();
    const int o = og * 64 + (tid >> 2), part = tid & 3;
    const float* wrow = Wc1 + (size_t)o * 3136 + 1024 + part * 528;
    float s = 0.f;
    for (int j = 0; j < 528; ++j) s += wrow[j] * v[part * 528 + j];
    red[tid] = s;
    __syncthreads();
    if (part == 0) {
        float tot = red[tid] + red[tid + 1] + red[tid + 2] + red[tid + 3];
        cvec[((size_t)b << 9) + o] = gc1[o] * (tot + bc1[o]) + bb1[o];
    }
}

// ---------------- launch ----------------
extern "C" void kernel_launch(void* const* d_in, const int* in_sizes, int n_in,
                              void* d_out, int out_size, void* d_ws, size_t ws_size,
                              hipStream_t stream)
{
    (void)in_sizes; (void)n_in; (void)out_size; (void)ws_size;
    const float* points = (const float*)d_in[0];
    const float* label  = (const float*)d_in[1];
    const float* We1 = (const float*)d_in[2];
    const float* ge1 = (const float*)d_in[3];
    const float* be1 = (const float*)d_in[4];
    const float* We2 = (const float*)d_in[5];
    const float* ge2 = (const float*)d_in[6];
    const float* be2 = (const float*)d_in[7];
    const float* W1  = (const float*)d_in[8];
    const float* g1  = (const float*)d_in[9];
    const float* b1  = (const float*)d_in[10];
    const float* W2  = (const float*)d_in[11];
    const float* g2  = (const float*)d_in[12];
    const float* b2  = (const float*)d_in[13];
    const float* Wf  = (const float*)d_in[14];
    const float* gf  = (const float*)d_in[15];
    const float* bfv = (const float*)d_in[16];
    const float* Wl  = (const float*)d_in[17];
    const float* gl  = (const float*)d_in[18];
    const float* bl  = (const float*)d_in[19];
    const float* Wc1 = (const float*)d_in[20];
    const float* bc1 = (const float*)d_in[21];
    const float* gc1 = (const float*)d_in[22];
    const float* bb1 = (const float*)d_in[23];
    const float* Wc2 = (const float*)d_in[24];
    const float* bc2 = (const float*)d_in[25];
    const float* gc2 = (const float*)d_in[26];
    const float* bb2 = (const float*)d_in[27];
    const float* Wc3 = (const float*)d_in[28];
    const float* bc3 = (const float*)d_in[29];

    char* ws = (char*)d_ws;
    _Float16* hT  = (_Float16*)(ws + OFF_HT);
    _Float16* tT  = (_Float16*)(ws + OFF_TT);
    _Float16* mT  = (_Float16*)(ws + OFF_MT);
    _Float16* xct = (_Float16*)(ws + OFF_XCAT);
    _Float16* xf  = (_Float16*)(ws + OFF_XF);
    _Float16* c1  = (_Float16*)(ws + OFF_C1);
    _Float16* c2  = (_Float16*)(ws + OFF_C2);
    int*      idx = (int*)     (ws + OFF_IDX);
    _Float16* x0  = (_Float16*)(ws + OFF_X0);

    _Float16* wE1 = (_Float16*)(ws + OFF_WE1);
    _Float16* wE2 = (_Float16*)(ws + OFF_WE2);
    _Float16* w1f = (_Float16*)(ws + OFF_W1);
    _Float16* w2f = (_Float16*)(ws + OFF_W2);
    _Float16* wF  = (_Float16*)(ws + OFF_WF);
    _Float16* wC1 = (_Float16*)(ws + OFF_WC1);
    _Float16* wC2 = (_Float16*)(ws + OFF_WC2);
    _Float16* wC3 = (_Float16*)(ws + OFF_WC3);
    float* bC2 = (float*)(ws + OFF_BC2);
    float* bC3 = (float*)(ws + OFF_BC3);
    float* cv  = (float*)(ws + OFF_CVEC);
    unsigned* pmx = (unsigned*)(ws + OFF_PMAX);
    float*    psm = (float*)   (ws + OFF_PSUM);

    // prep (weights + biases + x0 + pool-acc init, one launch)
    fold_all_kernel<<<dim3(4962), 256, 0, stream>>>(We1, ge1, We2, ge2, W1, g1, W2, g2,
                                                    Wf, gf, Wc1, gc1, Wc2, gc2, Wc3,
                                                    gc2, bc2, bb2, bc3, points, ws);
    knn_kernel<<<dim3(BB, NN / 32), 256, 0, stream>>>(points, idx);

    // e1: x0(Mx64,pad) -> tT(Mx128), relu
    gemm_tile<64, false><<<dim3(512, 1), 256, 0, stream>>>(wE1, x0, tT, nullptr, be1, nullptr, 64, 64, 0, 128, 0, 128, 1, 0, 0, 0, 128, nullptr, nullptr);
    // e2: tT -> hT, relu
    gemm_tile<64, false><<<dim3(512, 1), 256, 0, stream>>>(wE2, tT, hT, nullptr, be2, nullptr, 128, 128, 0, 128, 0, 128, 1, 0, 0, 0, 128, nullptr, nullptr);

    for (int i = 0; i < 3; ++i) {
        const _Float16* hin = (i == 0) ? hT : xct;
        int ldH  = (i == 0) ? 128 : 384;
        int offH = (i == 0) ? 0 : (i - 1) * 128;
        // t = relu(bn(W1 h))
        gemm_tile<64, false><<<dim3(512, 1), 256, 0, stream>>>(w1f + (size_t)i * 16384, hin, tT, nullptr, b1 + i * 128, nullptr,
                                                               128, ldH, offH, 128, 0, 128, 1, 0, 0, 0, 128, nullptr, nullptr);
        // m = neighbor max
        gather_max_kernel<<<dim3(MM / 16), 256, 0, stream>>>((const short*)tT, idx, (short*)mT);
        // h' = relu(bn(W2 m) + h) -> xcat slice i
        gemm_tile<64, false><<<dim3(512, 1), 256, 0, stream>>>(w2f + (size_t)i * 16384, mT, xct, nullptr, b2 + i * 128, hin,
                                                               128, 128, 0, 384, i * 128, 128, 1, 0, ldH, offH, 128, nullptr, nullptr);
    }

    // xf = leaky(bn(Wf xcat)) with fused max/mean pooling accumulation
    gemm_tile<128, true><<<dim3(256, 8), 256, 0, stream>>>(wF, xct, xf, nullptr, bfv, nullptr, 384, 384, 0, 1024, 0, 1024, 2, 0, 0, 0, 1024, pmx, psm);

    // per-batch classifier constant (consumes fused pool accumulators)
    cvec_kernel<<<dim3(BB, 8), 256, 0, stream>>>(label, Wl, gl, bl, Wc1, bc1, gc1, bb1, pmx, psm, cv);

    // c1 = relu(gc1*Wc1[:, :1024] xf + cvec[b])
    gemm_tile<128, false><<<dim3(256, 4), 256, 0, stream>>>(wC1, xf, c1, nullptr, cv, nullptr, 1024, 1024, 0, 512, 0, 512, 1, 1, 0, 0, 512, nullptr, nullptr);
    // c2 = relu(bn(Wc2 c1 + bc2))
    gemm_tile<128, false><<<dim3(256, 2), 256, 0, stream>>>(wC2, c1, c2, nullptr, bC2, nullptr, 512, 512, 0, 256, 0, 256, 1, 0, 0, 0, 256, nullptr, nullptr);
    // c3 = Wc3 c2 + bc3 (no act), f32, stored transposed directly to (B,50,N) output
    gemm_tile<128, false><<<dim3(256, 1), 256, 0, stream>>>(wC3, c2, nullptr, (float*)d_out, bC3, nullptr, 256, 256, 0, 0, 0, 128, 0, 0, 0, 0, 50, nullptr, nullptr);
}

// Round 14
// 442.271 us; speedup vs baseline: 1.0735x; 1.0079x over previous
//
#include <hip/hip_runtime.h>
#include <cstdint>
#include <cstddef>

#define DEVINL __device__ __forceinline__

typedef float    f32x4 __attribute__((ext_vector_type(4)));
typedef _Float16 f16x8 __attribute__((ext_vector_type(8)));
typedef _Float16 f16x4 __attribute__((ext_vector_type(4)));

// ---------------- constants ----------------
constexpr int BB = 16, NN = 2048, MM = 32768;

// ---------------- ws layout (bytes) ----------------
constexpr size_t OFF_WE1 = 0;                           // 128x64 f16 (Kp padded 6->64)
constexpr size_t OFF_WE2 = OFF_WE1 + 128 * 64 * 2;
constexpr size_t OFF_W1  = OFF_WE2 + 128 * 128 * 2;
constexpr size_t OFF_W2  = OFF_W1  + 3 * 128 * 128 * 2;
constexpr size_t OFF_WF  = OFF_W2  + 3 * 128 * 128 * 2;
constexpr size_t OFF_WC1 = OFF_WF  + 1024 * 384 * 2;
constexpr size_t OFF_WC2 = OFF_WC1 + 512 * 1024 * 2;
constexpr size_t OFF_WC3 = OFF_WC2 + 256 * 512 * 2;     // 128x256 (Opad 50->128)
constexpr size_t OFF_BC2 = OFF_WC3 + 128 * 256 * 2;     // 256 f32
constexpr size_t OFF_BC3 = OFF_BC2 + 256 * 4;           // 128 f32
constexpr size_t OFF_CVEC= OFF_BC3 + 128 * 4;           // 16x512 f32
constexpr size_t OFF_PMAX= OFF_CVEC+ 16 * 512 * 4;      // 16x1024 mapped-uint (atomic max)
constexpr size_t OFF_PSUM= OFF_PMAX+ 16 * 1024 * 4;     // 16x1024 f32 (atomic add)
constexpr size_t OFF_IDX = OFF_PSUM+ 16 * 1024 * 4;
constexpr size_t OFF_R1  = 8ull << 20;                  // > OFF_IDX + 2MB
constexpr size_t OFF_X0  = OFF_R1;                      // 4MB  (M x 64 f16, k-padded)
constexpr size_t OFF_HT  = OFF_R1 + (4ull  << 20);      // 8MB  (M x 128 f16)
constexpr size_t OFF_TT  = OFF_R1 + (12ull << 20);      // 8MB
constexpr size_t OFF_MT  = OFF_R1 + (20ull << 20);      // 8MB
constexpr size_t OFF_C1  = OFF_R1;                      // 32MB (M x 512 f16), aliases x0/h/t/m (dead)
constexpr size_t OFF_XCAT= OFF_R1 + (32ull << 20);      // 24MB (M x 384 f16)
constexpr size_t OFF_C2  = OFF_XCAT;                    // 16MB (M x 256 f16), aliases xcat (dead)
constexpr size_t OFF_XF  = OFF_XCAT + (24ull << 20);    // 64MB (M x 1024 f16)

DEVINL unsigned fmap(float f) {            // order-preserving float->uint
    unsigned u = __float_as_uint(f);
    return (u & 0x80000000u) ? ~u : (u | 0x80000000u);
}
DEVINL float funmap(unsigned u) {
    return (u & 0x80000000u) ? __uint_as_float(u & 0x7FFFFFFFu) : __uint_as_float(~u);
}

// ---------------- KNN helpers (exact distances; select + threshold rescan) ----------------
DEVINL float knn_dist(const float4 pq, const float4 pm) {
    float t = pq.x * pm.x;
    t = fmaf(pq.y, pm.y, t);
    t = fmaf(pq.z, pm.z, t);
    return fmaf(-2.f, t, pm.w);
}

#define KNN_DINS(X) do { \
    const float x_ = (X); \
    d15 = __builtin_amdgcn_fmed3f(x_, d14, d15); \
    d14 = __builtin_amdgcn_fmed3f(x_, d13, d14); \
    d13 = __builtin_amdgcn_fmed3f(x_, d12, d13); \
    d12 = __builtin_amdgcn_fmed3f(x_, d11, d12); \
    d11 = __builtin_amdgcn_fmed3f(x_, d10, d11); \
    d10 = __builtin_amdgcn_fmed3f(x_, d9,  d10); \
    d9  = __builtin_amdgcn_fmed3f(x_, d8,  d9);  \
    d8  = __builtin_amdgcn_fmed3f(x_, d7,  d8);  \
    d7  = __builtin_amdgcn_fmed3f(x_, d6,  d7);  \
    d6  = __builtin_amdgcn_fmed3f(x_, d5,  d6);  \
    d5  = __builtin_amdgcn_fmed3f(x_, d4,  d5);  \
    d4  = __builtin_amdgcn_fmed3f(x_, d3,  d4);  \
    d3  = __builtin_amdgcn_fmed3f(x_, d2,  d3);  \
    d2  = __builtin_amdgcn_fmed3f(x_, d1,  d2);  \
    d1  = __builtin_amdgcn_fmed3f(x_, d0,  d1);  \
    d0  = __builtin_amdgcn_fmed3f(x_, -3.4e38f, d0); \
} while (0)

#define KNN_CE(A, B) { const float lo_ = fminf(A, B), hi_ = fmaxf(A, B); A = lo_; B = hi_; }

#define KNN_MERGE(OFF) do { \
    const float n0  = __shfl_xor(d0,  OFF), n1  = __shfl_xor(d1,  OFF), \
                n2  = __shfl_xor(d2,  OFF), n3  = __shfl_xor(d3,  OFF), \
                n4  = __shfl_xor(d4,  OFF), n5  = __shfl_xor(d5,  OFF), \
                n6  = __shfl_xor(d6,  OFF), n7  = __shfl_xor(d7,  OFF), \
                n8  = __shfl_xor(d8,  OFF), n9  = __shfl_xor(d9,  OFF), \
                n10 = __shfl_xor(d10, OFF), n11 = __shfl_xor(d11, OFF), \
                n12 = __shfl_xor(d12, OFF), n13 = __shfl_xor(d13, OFF), \
                n14 = __shfl_xor(d14, OFF), n15 = __shfl_xor(d15, OFF); \
    d0  = fminf(d0,  n15); d1  = fminf(d1,  n14); d2  = fminf(d2,  n13); d3  = fminf(d3,  n12); \
    d4  = fminf(d4,  n11); d5  = fminf(d5,  n10); d6  = fminf(d6,  n9);  d7  = fminf(d7,  n8);  \
    d8  = fminf(d8,  n7);  d9  = fminf(d9,  n6);  d10 = fminf(d10, n5);  d11 = fminf(d11, n4);  \
    d12 = fminf(d12, n3);  d13 = fminf(d13, n2);  d14 = fminf(d14, n1);  d15 = fminf(d15, n0);  \
    KNN_CE(d0, d8)  KNN_CE(d1, d9)  KNN_CE(d2, d10) KNN_CE(d3, d11) \
    KNN_CE(d4, d12) KNN_CE(d5, d13) KNN_CE(d6, d14) KNN_CE(d7, d15) \
    KNN_CE(d0, d4)  KNN_CE(d1, d5)  KNN_CE(d2, d6)  KNN_CE(d3, d7)  \
    KNN_CE(d8, d12) KNN_CE(d9, d13) KNN_CE(d10,d14) KNN_CE(d11,d15) \
    KNN_CE(d0, d2)  KNN_CE(d1, d3)  KNN_CE(d4, d6)  KNN_CE(d5, d7)  \
    KNN_CE(d8, d10) KNN_CE(d9, d11) KNN_CE(d12,d14) KNN_CE(d13,d15) \
    KNN_CE(d0, d1)  KNN_CE(d2, d3)  KNN_CE(d4, d5)  KNN_CE(d6, d7)  \
    KNN_CE(d8, d9)  KNN_CE(d10,d11) KNN_CE(d12,d13) KNN_CE(d14,d15) \
} while (0)

// ---------------- prep+knn merged kernel ----------------
// bids [0,1024): KNN (LDS-heavy, 4 blocks/CU, 16 waves/CU) — issued first.
// bids [1024, 5986): weight folding / biases / x0 prep / pool-acc init —
// 0-LDS-use blocks that co-schedule in the spare wave slots under KNN.
__global__ __launch_bounds__(256) void prep_knn_kernel(
    const float* We1, const float* ge1, const float* We2, const float* ge2,
    const float* W1,  const float* g1,  const float* W2,  const float* g2,
    const float* Wf,  const float* gf,  const float* Wc1, const float* gc1,
    const float* Wc2, const float* gc2, const float* Wc3,
    const float* gc2b, const float* bc2, const float* bb2, const float* bc3,
    const float* pts, int* idxout, char* ws)
{
    __shared__ float4 P[2048];
    __shared__ int    cnt[32];
    const int bid = blockIdx.x;
    const int tid = threadIdx.x;

    if (bid < 1024) {
        // ---- KNN: exact select (med3 network) + tournament merge + threshold rescan ----
        const int b = bid >> 6;
        const float* pb = pts + (size_t)b * 6 * 2048;
        for (int i = tid; i < 2048; i += 256) {
            float x = pb[i];
            float y = pb[2048 + i];
            float z = pb[4096 + i];
            P[i] = make_float4(x, y, z, x * x + y * y + z * z);
        }
        if (tid < 32) cnt[tid] = 0;
        __syncthreads();

        const int p = tid & 7;          // candidate partition (m == 8*it + p)
        const int g = tid >> 3;         // query within block (0..31)
        const int q = (bid & 63) * 32 + g;
        const float4 pq = P[q];

        float d0 = 3.4e38f, d1 = 3.4e38f, d2 = 3.4e38f, d3 = 3.4e38f,
              d4 = 3.4e38f, d5 = 3.4e38f, d6 = 3.4e38f, d7 = 3.4e38f,
              d8 = 3.4e38f, d9 = 3.4e38f, d10 = 3.4e38f, d11 = 3.4e38f,
              d12 = 3.4e38f, d13 = 3.4e38f, d14 = 3.4e38f, d15 = 3.4e38f;

        float4 nxt = P[p];
#pragma unroll 2
        for (int it = 0; it < 256; ++it) {
            const float4 pm = nxt;
            const int m = it * 8 + p;
            nxt = P[(m + 8) & 2047];    // prefetch next candidate (wraps harmlessly on last)
            KNN_DINS(knn_dist(pq, pm));
        }

        KNN_MERGE(1);
        KNN_MERGE(2);
        KNN_MERGE(4);
        // every lane now holds the global sorted top-16 distances; d15 = threshold

        const float t = d15;
        int* op = idxout + (((size_t)(b << 11) + q) << 4);
        float4 nxt2 = P[p];
        for (int it = 0; it < 256; ++it) {
            const float4 pm = nxt2;
            const int m = it * 8 + p;
            nxt2 = P[(m + 8) & 2047];
            const float d = knn_dist(pq, pm);
            if (d <= t) {
                const int pos = atomicAdd(&cnt[g], 1);
                if (pos < 16) op[pos] = m;   // order-scrambled: consumer is a max over the set
            }
        }
        return;
    }

    // ---- prep section (block ids shifted by 1024) ----
    const int fid = bid - 1024;

    if (fid == 4704) {
        ((float*)(ws + OFF_BC2))[tid] = gc2b[tid] * bc2[tid] + bb2[tid];
        return;
    }
    if (fid == 4705) {
        if (tid < 128) ((float*)(ws + OFF_BC3))[tid] = (tid < 50) ? bc3[tid] : 0.f;
        return;
    }
    if (fid >= 4834) {           // pool accumulator init: pmax (mapped) = 0, psum = 0
        int f = (fid - 4834) * 256 + tid;
        if (f < 16384) ((unsigned*)(ws + OFF_PMAX))[f] = 0u;
        else           ((float*)   (ws + OFF_PSUM))[f - 16384] = 0.f;
        return;
    }
    if (fid >= 4706) {           // x0 prep: (B,6,N) f32 -> (M x 64) f16 K-contig, zero pad
        int m = (fid - 4706) * 256 + tid;
        int b = m >> 11, n = m & 2047;
        const float* ps = pts + (size_t)b * 6 * 2048 + n;
        _Float16 tmp[64];
#pragma unroll
        for (int c = 0; c < 64; ++c) tmp[c] = (_Float16)0.f;
#pragma unroll
        for (int c = 0; c < 6; ++c) tmp[c] = (_Float16)ps[(size_t)c << 11];
        _Float16* dst = (_Float16*)(ws + OFF_X0) + (size_t)m * 64;
#pragma unroll
        for (int v = 0; v < 8; ++v) *(f16x8*)(dst + v * 8) = *(const f16x8*)(tmp + v * 8);
        return;
    }

    int id, base;
    if      (fid < 32)   { id = 0;  base = 0;    }
    else if (fid < 96)   { id = 1;  base = 32;   }
    else if (fid < 160)  { id = 2;  base = 96;   }
    else if (fid < 224)  { id = 3;  base = 160;  }
    else if (fid < 288)  { id = 4;  base = 224;  }
    else if (fid < 352)  { id = 5;  base = 288;  }
    else if (fid < 416)  { id = 6;  base = 352;  }
    else if (fid < 480)  { id = 7;  base = 416;  }
    else if (fid < 2016) { id = 8;  base = 480;  }
    else if (fid < 4064) { id = 9;  base = 2016; }
    else if (fid < 4576) { id = 10; base = 4064; }
    else                 { id = 11; base = 4576; }

    const float* src = nullptr; const float* g = nullptr; _Float16* dst = nullptr;
    int O = 0, K = 0, lds = 0, Kp = 0;
    switch (id) {
        case 0:  src = We1; g = ge1; O = 128; K = 6;    lds = 6;    Kp = 64;   dst = (_Float16*)(ws + OFF_WE1); break;
        case 1:  src = We2; g = ge2; O = 128; K = 128;  lds = 128;  Kp = 128;  dst = (_Float16*)(ws + OFF_WE2); break;
        case 2: case 3: case 4: {
            int i = id - 2;
            src = W1 + (size_t)i * 16384; g = g1 + i * 128; O = 128; K = 128; lds = 128; Kp = 128;
            dst = (_Float16*)(ws + OFF_W1) + (size_t)i * 16384; break; }
        case 5: case 6: case 7: {
            int i = id - 5;
            src = W2 + (size_t)i * 16384; g = g2 + i * 128; O = 128; K = 128; lds = 128; Kp = 128;
            dst = (_Float16*)(ws + OFF_W2) + (size_t)i * 16384; break; }
        case 8:  src = Wf;  g = gf;  O = 1024; K = 384;  lds = 384;  Kp = 384;  dst = (_Float16*)(ws + OFF_WF);  break;
        case 9:  src = Wc1; g = gc1; O = 512;  K = 1024; lds = 3136; Kp = 1024; dst = (_Float16*)(ws + OFF_WC1); break;
        case 10: src = Wc2; g = gc2; O = 256;  K = 512;  lds = 512;  Kp = 512;  dst = (_Float16*)(ws + OFF_WC2); break;
        default: src = Wc3; g = nullptr; O = 50; K = 256; lds = 256; Kp = 256;  dst = (_Float16*)(ws + OFF_WC3); break;
    }
    int e = (fid - base) * 256 + tid;
    int o = e / Kp, k = e - o * Kp;
    float v = 0.f;
    if (o < O && k < K) {
        v = src[(size_t)o * lds + k];
        if (g) v *= g[o];
    }
    dst[e] = (_Float16)v;
}

// ---------------- GEMM: TM(64|128) x 128o tile, BK=64, global_load_lds staging.
// Grid: x = m-blocks (fast-varying; weights reused via L2), y = o-blocks.
// POOL: fused per-column max/sum over m (LDS cross-wave combine -> one atomic pair/o/block).
template<int TM, bool POOL>
__global__ __launch_bounds__(256) void gemm_tile(
    const _Float16* __restrict__ W, const _Float16* __restrict__ X,
    _Float16* __restrict__ Y, float* __restrict__ Y32,
    const float* __restrict__ bias, const _Float16* __restrict__ Res,
    int Kp, int ldX, int xoff, int ldY, int yoff, int Opad,
    int act, int biasPerBatch, int ldR, int roff, int Olimit,
    unsigned* __restrict__ pmaxG, float* __restrict__ psumG)
{
    constexpr int MI = TM / 32;                 // m-frags per wave
    __shared__ _Float16 SH[128 * 64 + TM * 64]; // As | Bs ; reused as output tile
    __shared__ float PM[POOL ? 256 : 1];        // cross-wave pool combine
    _Float16* As = SH;
    _Float16* Bs = SH + 128 * 64;

    const int tid  = threadIdx.x;
    const int lane = tid & 63, wave = tid >> 6;
    const int r = lane & 15, quad = lane >> 4;
    const int m_blk = blockIdx.x * TM, o_blk = blockIdx.y * 128;
    const int oh = (wave >> 1) * 64, mh = (wave & 1) * (TM / 2);

    f32x4 acc[4][MI];
#pragma unroll
    for (int a = 0; a < 4; ++a)
#pragma unroll
        for (int c = 0; c < MI; ++c) acc[a][c] = (f32x4){0.f, 0.f, 0.f, 0.f};

    const int srow  = wave * 8 + (lane >> 3);
    const int sslot = lane & 7;

    for (int k0 = 0; k0 < Kp; k0 += 64) {
        __syncthreads();
#pragma unroll
        for (int t = 0; t < 4; ++t) {           // A: 128 rows
            const int rowA = t * 32 + srow;
            const int gk = k0 + ((sslot ^ (rowA & 7)) << 3);
            const _Float16* gA = W + (size_t)(o_blk + rowA) * Kp + gk;
            __builtin_amdgcn_global_load_lds(
                (const __attribute__((address_space(1))) unsigned int*)gA,
                (__attribute__((address_space(3))) unsigned int*)(As + t * 2048 + wave * 512),
                16, 0, 0);
        }
#pragma unroll
        for (int t = 0; t < TM / 32; ++t) {     // B: TM rows
            const int rowB = t * 32 + srow;
            const int gk = k0 + ((sslot ^ (rowB & 7)) << 3);
            const _Float16* gB = X + (size_t)(m_blk + rowB) * ldX + xoff + gk;
            __builtin_amdgcn_global_load_lds(
                (const __attribute__((address_space(1))) unsigned int*)gB,
                (__attribute__((address_space(3))) unsigned int*)(Bs + t * 2048 + wave * 512),
                16, 0, 0);
        }
        __syncthreads();
#pragma unroll
        for (int ks = 0; ks < 2; ++ks) {
            f16x8 af[4], bf[MI];
#pragma unroll
            for (int oi = 0; oi < 4; ++oi) {
                const int row = oh + oi * 16 + r;
                const int slot = (ks * 4 + quad) ^ (row & 7);
                af[oi] = *(const f16x8*)(As + row * 64 + slot * 8);
            }
#pragma unroll
            for (int mi = 0; mi < MI; ++mi) {
                const int row = mh + mi * 16 + r;
                const int slot = (ks * 4 + quad) ^ (row & 7);
                bf[mi] = *(const f16x8*)(Bs + row * 64 + slot * 8);
            }
#pragma unroll
            for (int oi = 0; oi < 4; ++oi)
#pragma unroll
                for (int mi = 0; mi < MI; ++mi)
                    acc[oi][mi] = __builtin_amdgcn_mfma_f32_16x16x32_f16(af[oi], bf[mi], acc[oi][mi], 0, 0, 0);
        }
    }

    const int bb = biasPerBatch ? (m_blk >> 11) * Opad : 0;
    __syncthreads();   // done reading As/Bs; SH is reusable

    if (Y32) {
        // f32 path: store transposed to (B, 50, N): Y32[(b*50+o)*2048 + n], o < Olimit
#pragma unroll
        for (int oi = 0; oi < 4; ++oi) {
            const int og = o_blk + oh + oi * 16 + quad * 4;
            const f32x4 bv = *(const f32x4*)(bias + bb + og);
#pragma unroll
            for (int mi = 0; mi < MI; ++mi) {
                const int m = m_blk + mh + mi * 16 + r;
                const int bidx = m >> 11, n = m & 2047;
                f32x4 v = acc[oi][mi] + bv;
#pragma unroll
                for (int j = 0; j < 4; ++j) {
                    float x = v[j];
                    if (act == 1)      x = (x > 0.f) ? x : 0.0f;
                    else if (act == 2) x = (x > 0.f) ? x : 0.2f * x;
                    const int o = og + j;
                    if (o < Olimit)
                        Y32[((size_t)(bidx * 50 + o) << 11) + n] = x;
                }
            }
        }
        return;
    }

    // f16 path: stage [TM][128] tile in LDS (XOR-swizzled), then coalesced writeback
    float cmax[4][4], csum[4][4];
    if (POOL) {
#pragma unroll
        for (int a = 0; a < 4; ++a)
#pragma unroll
            for (int j = 0; j < 4; ++j) { cmax[a][j] = -3.4e38f; csum[a][j] = 0.f; }
    }
    _Float16* OT = SH;
#pragma unroll
    for (int oi = 0; oi < 4; ++oi) {
        const int ol = oh + oi * 16 + quad * 4;       // local o (0..127), 4-aligned
        const f32x4 bv = *(const f32x4*)(bias + bb + o_blk + ol);
#pragma unroll
        for (int mi = 0; mi < MI; ++mi) {
            const int row = mh + mi * 16 + r;         // local m
            f32x4 v = acc[oi][mi] + bv;
            if (Res) {
                f16x4 rr = *(const f16x4*)(Res + (size_t)(m_blk + row) * ldR + roff + o_blk + ol);
#pragma unroll
                for (int j = 0; j < 4; ++j) v[j] += (float)rr[j];
            }
            f16x4 ov;
#pragma unroll
            for (int j = 0; j < 4; ++j) {
                float x = v[j];
                if (act == 1)      x = (x > 0.f) ? x : 0.0f;
                else if (act == 2) x = (x > 0.f) ? x : 0.2f * x;
                ov[j] = (_Float16)x;
                if (POOL) { cmax[oi][j] = fmaxf(cmax[oi][j], x); csum[oi][j] += x; }
            }
            const int s = ((ol >> 2) ^ (row & 31)) << 2;   // swizzled 8B slot
            *(f16x4*)(OT + row * 128 + s) = ov;
        }
    }

    if (POOL) {
        // reduce over the 16 r-lanes
#pragma unroll
        for (int mask = 1; mask <= 8; mask <<= 1) {
#pragma unroll
            for (int a = 0; a < 4; ++a)
#pragma unroll
                for (int j = 0; j < 4; ++j) {
                    cmax[a][j] = fmaxf(cmax[a][j], __shfl_xor(cmax[a][j], mask));
                    csum[a][j] += __shfl_xor(csum[a][j], mask);
                }
        }
        // cross-wave combine: waves {0,2} (mh=0) write, waves {1,3} (mh=64) merge+atomic
        if (r == 0 && (wave & 1) == 0) {
#pragma unroll
            for (int a = 0; a < 4; ++a)
#pragma unroll
                for (int j = 0; j < 4; ++j) {
                    const int ol = oh + a * 16 + quad * 4 + j;     // 0..127
                    PM[ol] = cmax[a][j];
                    PM[128 + ol] = csum[a][j];
                }
        }
        __syncthreads();
        if (r == 0 && (wave & 1) == 1) {
            const int bidx = m_blk >> 11;
#pragma unroll
            for (int a = 0; a < 4; ++a)
#pragma unroll
                for (int j = 0; j < 4; ++j) {
                    const int ol = oh + a * 16 + quad * 4 + j;
                    const int o = o_blk + ol;
                    atomicMax(&pmaxG[(bidx << 10) + o], fmap(fmaxf(cmax[a][j], PM[ol])));
                    atomicAdd(&psumG[(bidx << 10) + o], csum[a][j] + PM[128 + ol]);
                }
        }
    }

    __syncthreads();
#pragma unroll
    for (int it2 = 0; it2 < TM / 16; ++it2) {
        const int row = it2 * 16 + (tid >> 4);
        const int c = tid & 15;                        // 8 f16 per lane, contiguous
        const int s0 = ((c * 2) ^ (row & 31)) << 2;
        const int s1 = ((c * 2 + 1) ^ (row & 31)) << 2;
        f16x4 a = *(const f16x4*)(OT + row * 128 + s0);
        f16x4 b2 = *(const f16x4*)(OT + row * 128 + s1);
        f16x8 o8;
        o8[0] = a[0]; o8[1] = a[1]; o8[2] = a[2]; o8[3] = a[3];
        o8[4] = b2[0]; o8[5] = b2[1]; o8[6] = b2[2]; o8[7] = b2[3];
        *(f16x8*)(Y + (size_t)(m_blk + row) * ldY + yoff + o_blk + c * 8) = o8;
    }
}

// ---------------- neighbor gather + channel max (relu outputs => ushort-monotonic f16 bits) ----------------
typedef short s16x8 __attribute__((ext_vector_type(8)));
__global__ __launch_bounds__(256) void gather_max_kernel(
    const short* __restrict__ T, const int* __restrict__ idx, short* __restrict__ Mo)
{
    const int tid = threadIdx.x;
    const int p = blockIdx.x * 16 + (tid >> 4);
    const int l = tid & 15;
    const int b = p >> 11;
    const int* ip = idx + (size_t)p * 16;
    size_t row = (size_t)((b << 11) + ip[0]);
    s16x8 cur = *(const s16x8*)(T + row * 128 + l * 8);
    unsigned short best[8];
#pragma unroll
    for (int e = 0; e < 8; ++e) best[e] = (unsigned short)cur[e];
#pragma unroll
    for (int j = 1; j < 16; ++j) {
        row = (size_t)((b << 11) + ip[j]);
        s16x8 v = *(const s16x8*)(T + row * 128 + l * 8);
#pragma unroll
        for (int e = 0; e < 8; ++e) {
            unsigned short u = (unsigned short)v[e];
            if (u > best[e]) best[e] = u;
        }
    }
    s16x8 ov;
#pragma unroll
    for (int e = 0; e < 8; ++e) ov[e] = (short)best[e];
    *(s16x8*)(Mo + (size_t)p * 128 + l * 8) = ov;
}

// ---------------- per-batch constant vector for Wc1 (reads fused pool accumulators) ----------------
__global__ __launch_bounds__(256) void cvec_kernel(
    const float* __restrict__ label, const float* __restrict__ Wl, const float* __restrict__ gl, const float* __restrict__ bl,
    const float* __restrict__ Wc1, const float* __restrict__ bc1, const float* __restrict__ gc1, const float* __restrict__ bb1,
    const unsigned* __restrict__ pmax, const float* __restrict__ psum, float* __restrict__ cvec)
{
    __shared__ float v[2112];
    __shared__ float red[256];
    const int b = blockIdx.x, og = blockIdx.y, tid = threadIdx.x;
    for (int i = tid; i < 1024; i += 256) {
        v[i] = funmap(pmax[((size_t)b << 10) + i]);
        v[1024 + i] = psum[((size_t)b << 10) + i] * (1.f / 2048.f);
    }
    if (tid < 64) {
        float s = 0.f;
        for (int i = 0; i < 16; ++i) s += Wl[tid * 16 + i] * label[b * 16 + i];
        s = gl[tid] * s + bl[tid];
        v[2048 + tid] = (s > 0.f) ? s : 0.2f * s;
    }
    __syncthreads();
    const int o = og * 64 + (tid >> 2), part = tid & 3;
    const float* wrow = Wc1 + (size_t)o * 3136 + 1024 + part * 528;
    float s = 0.f;
    for (int j = 0; j < 528; ++j) s += wrow[j] * v[part * 528 + j];
    red[tid] = s;
    __syncthreads();
    if (part == 0) {
        float tot = red[tid] + red[tid + 1] + red[tid + 2] + red[tid + 3];
        cvec[((size_t)b << 9) + o] = gc1[o] * (tot + bc1[o]) + bb1[o];
    }
}

// ---------------- launch ----------------
extern "C" void kernel_launch(void* const* d_in, const int* in_sizes, int n_in,
                              void* d_out, int out_size, void* d_ws, size_t ws_size,
                              hipStream_t stream)
{
    (void)in_sizes; (void)n_in; (void)out_size; (void)ws_size;
    const float* points = (const float*)d_in[0];
    const float* label  = (const float*)d_in[1];
    const float* We1 = (const float*)d_in[2];
    const float* ge1 = (const float*)d_in[3];
    const float* be1 = (const float*)d_in[4];
    const float* We2 = (const float*)d_in[5];
    const float* ge2 = (const float*)d_in[6];
    const float* be2 = (const float*)d_in[7];
    const float* W1  = (const float*)d_in[8];
    const float* g1  = (const float*)d_in[9];
    const float* b1  = (const float*)d_in[10];
    const float* W2  = (const float*)d_in[11];
    const float* g2  = (const float*)d_in[12];
    const float* b2  = (const float*)d_in[13];
    const float* Wf  = (const float*)d_in[14];
    const float* gf  = (const float*)d_in[15];
    const float* bfv = (const float*)d_in[16];
    const float* Wl  = (const float*)d_in[17];
    const float* gl  = (const float*)d_in[18];
    const float* bl  = (const float*)d_in[19];
    const float* Wc1 = (const float*)d_in[20];
    const float* bc1 = (const float*)d_in[21];
    const float* gc1 = (const float*)d_in[22];
    const float* bb1 = (const float*)d_in[23];
    const float* Wc2 = (const float*)d_in[24];
    const float* bc2 = (const float*)d_in[25];
    const float* gc2 = (const float*)d_in[26];
    const float* bb2 = (const float*)d_in[27];
    const float* Wc3 = (const float*)d_in[28];
    const float* bc3 = (const float*)d_in[29];

    char* ws = (char*)d_ws;
    _Float16* hT  = (_Float16*)(ws + OFF_HT);
    _Float16* tT  = (_Float16*)(ws + OFF_TT);
    _Float16* mT  = (_Float16*)(ws + OFF_MT);
    _Float16* xct = (_Float16*)(ws + OFF_XCAT);
    _Float16* xf  = (_Float16*)(ws + OFF_XF);
    _Float16* c1  = (_Float16*)(ws + OFF_C1);
    _Float16* c2  = (_Float16*)(ws + OFF_C2);
    int*      idx = (int*)     (ws + OFF_IDX);
    _Float16* x0  = (_Float16*)(ws + OFF_X0);

    _Float16* wE1 = (_Float16*)(ws + OFF_WE1);
    _Float16* wE2 = (_Float16*)(ws + OFF_WE2);
    _Float16* w1f = (_Float16*)(ws + OFF_W1);
    _Float16* w2f = (_Float16*)(ws + OFF_W2);
    _Float16* wF  = (_Float16*)(ws + OFF_WF);
    _Float16* wC1 = (_Float16*)(ws + OFF_WC1);
    _Float16* wC2 = (_Float16*)(ws + OFF_WC2);
    _Float16* wC3 = (_Float16*)(ws + OFF_WC3);
    float* bC2 = (float*)(ws + OFF_BC2);
    float* bC3 = (float*)(ws + OFF_BC3);
    float* cv  = (float*)(ws + OFF_CVEC);
    unsigned* pmx = (unsigned*)(ws + OFF_PMAX);
    float*    psm = (float*)   (ws + OFF_PSUM);

    // prep + knn, one launch: knn blocks (0..1023) grab LDS first; prep blocks
    // co-schedule in the spare wave slots.
    prep_knn_kernel<<<dim3(1024 + 4962), 256, 0, stream>>>(
        We1, ge1, We2, ge2, W1, g1, W2, g2, Wf, gf, Wc1, gc1, Wc2, gc2, Wc3,
        gc2, bc2, bb2, bc3, points, idx, ws);

    // e1: x0(Mx64,pad) -> tT(Mx128), relu
    gemm_tile<64, false><<<dim3(512, 1), 256, 0, stream>>>(wE1, x0, tT, nullptr, be1, nullptr, 64, 64, 0, 128, 0, 128, 1, 0, 0, 0, 128, nullptr, nullptr);
    // e2: tT -> hT, relu
    gemm_tile<64, false><<<dim3(512, 1), 256, 0, stream>>>(wE2, tT, hT, nullptr, be2, nullptr, 128, 128, 0, 128, 0, 128, 1, 0, 0, 0, 128, nullptr, nullptr);

    for (int i = 0; i < 3; ++i) {
        const _Float16* hin = (i == 0) ? hT : xct;
        int ldH  = (i == 0) ? 128 : 384;
        int offH = (i == 0) ? 0 : (i - 1) * 128;
        // t = relu(bn(W1 h))
        gemm_tile<64, false><<<dim3(512, 1), 256, 0, stream>>>(w1f + (size_t)i * 16384, hin, tT, nullptr, b1 + i * 128, nullptr,
                                                               128, ldH, offH, 128, 0, 128, 1, 0, 0, 0, 128, nullptr, nullptr);
        // m = neighbor max
        gather_max_kernel<<<dim3(MM / 16), 256, 0, stream>>>((const short*)tT, idx, (short*)mT);
        // h' = relu(bn(W2 m) + h) -> xcat slice i
        gemm_tile<64, false><<<dim3(512, 1), 256, 0, stream>>>(w2f + (size_t)i * 16384, mT, xct, nullptr, b2 + i * 128, hin,
                                                               128, 128, 0, 384, i * 128, 128, 1, 0, ldH, offH, 128, nullptr, nullptr);
    }

    // xf = leaky(bn(Wf xcat)) with fused max/mean pooling accumulation
    gemm_tile<128, true><<<dim3(256, 8), 256, 0, stream>>>(wF, xct, xf, nullptr, bfv, nullptr, 384, 384, 0, 1024, 0, 1024, 2, 0, 0, 0, 1024, pmx, psm);

    // per-batch classifier constant (consumes fused pool accumulators)
    cvec_kernel<<<dim3(BB, 8), 256, 0, stream>>>(label, Wl, gl, bl, Wc1, bc1, gc1, bb1, pmx, psm, cv);

    // c1 = relu(gc1*Wc1[:, :1024] xf + cvec[b])
    gemm_tile<128, false><<<dim3(256, 4), 256, 0, stream>>>(wC1, xf, c1, nullptr, cv, nullptr, 1024, 1024, 0, 512, 0, 512, 1, 1, 0, 0, 512, nullptr, nullptr);
    // c2 = relu(bn(Wc2 c1 + bc2))
    gemm_tile<128, false><<<dim3(256, 2), 256, 0, stream>>>(wC2, c1, c2, nullptr, bC2, nullptr, 512, 512, 0, 256, 0, 256, 1, 0, 0, 0, 256, nullptr, nullptr);
    // c3 = Wc3 c2 + bc3 (no act), f32, stored transposed directly to (B,50,N) output
    gemm_tile<128, false><<<dim3(256, 1), 256, 0, stream>>>(wC3, c2, nullptr, (float*)d_out, bC3, nullptr, 256, 256, 0, 0, 0, 128, 0, 0, 0, 0, 50, nullptr, nullptr);
}